// Round 6
// baseline (562.323 us; speedup 1.0000x reference)
//
#include <hip/hip_runtime.h>
#include <math.h>

typedef __bf16 bf16;
typedef __bf16 bf16x8 __attribute__((ext_vector_type(8)));
typedef __bf16 bf16x4 __attribute__((ext_vector_type(4)));
typedef __bf16 bf16x2 __attribute__((ext_vector_type(2)));
typedef float f32x4 __attribute__((ext_vector_type(4)));
typedef float f32x2 __attribute__((ext_vector_type(2)));
typedef unsigned int u32;

#define N_NODES 10000
#define N_EDGES 80000
#define N_GRAPHS 64

template<int EPL> struct VecT;
template<> struct VecT<8>{ typedef bf16x8 type; };
template<> struct VecT<4>{ typedef bf16x4 type; };
template<> struct VecT<2>{ typedef bf16x2 type; };

__device__ inline void gload_lds16(const bf16* g, bf16* l){
  __builtin_amdgcn_global_load_lds(
      (const __attribute__((address_space(1))) unsigned int*)g,
      (__attribute__((address_space(3))) unsigned int*)l, 16, 0, 0);
}

__global__ __launch_bounds__(256) void detect_f32_k(const unsigned short* __restrict__ raw, int n,
                                                    int* __restrict__ flagF){
  int i = blockIdx.x*256 + threadIdx.x;
  if (i < n){
    unsigned e = (raw[i] >> 7) & 0xFFu;
    if (e >= 0xC0u) atomicOr(flagF, 1);
  }
}

// ---- batched conversion with strided-dst support ----
struct CvPack {
  const void* src[11];
  bf16* dst[11];
  int pre[12];
  int rl[11];
  int st[11];
};
__global__ __launch_bounds__(256) void convert_all(CvPack p, const int* __restrict__ flagF){
  int gid = blockIdx.x*256 + threadIdx.x;
  if (gid >= p.pre[11]) return;
  int t = 0;
  while (gid >= p.pre[t+1]) ++t;
  int i = gid - p.pre[t];
  bool f = (*flagF != 0);
  float v = f ? ((const float*)p.src[t])[i] : (float)((const bf16*)p.src[t])[i];
  int row = i / p.rl[t], col = i - row*p.rl[t];
  p.dst[t][(size_t)row*p.st[t] + col] = (bf16)v;
}

__global__ __launch_bounds__(256) void detect_i64(const int* __restrict__ raw, int* __restrict__ flag){
  int i = blockIdx.x*256 + threadIdx.x;
  if (i < 4000 && raw[2*i+1] != 0) atomicOr(flag, 1);   // flag!=0 => int32
}

// conv_idx + degree count fused (cnt pre-zeroed via memset)
__global__ __launch_bounds__(256) void conv_idx(const int* __restrict__ ei_raw,
                                                const int* __restrict__ b_raw,
                                                const int* __restrict__ flag,
                                                int* __restrict__ src, int* __restrict__ dst,
                                                int* __restrict__ bat, int* __restrict__ cnt){
  int i = blockIdx.x*256 + threadIdx.x;
  bool i32 = (*flag != 0);
  if (i < N_EDGES){
    int s = i32 ? ei_raw[i]   : ei_raw[2*i];
    int d = i32 ? ei_raw[N_EDGES + i] : ei_raw[2*(N_EDGES + i)];
    s = min(max(s, 0), N_NODES-1);
    d = min(max(d, 0), N_NODES-1);
    src[i] = s; dst[i] = d;
    atomicAdd(&cnt[d], 1);
  }
  if (i < N_NODES){
    int b = i32 ? b_raw[i] : b_raw[2*i];
    bat[i] = min(max(b, 0), N_GRAPHS-1);
  }
}

// ---------------- parallel scan (3 small dispatches) ----------------
__global__ __launch_bounds__(256) void scanA(const int* __restrict__ cnt, int* __restrict__ fill,
                                             int* __restrict__ bsum, int N){
  __shared__ int s[256];
  int i = blockIdx.x*256 + threadIdx.x;
  int v = (i < N) ? cnt[i] : 0;
  s[threadIdx.x] = v;
  __syncthreads();
  for (int d = 1; d < 256; d <<= 1){
    int t = (threadIdx.x >= d) ? s[threadIdx.x - d] : 0;
    __syncthreads();
    s[threadIdx.x] += t;
    __syncthreads();
  }
  if (i < N) fill[i] = s[threadIdx.x] - v;          // block-exclusive
  if (threadIdx.x == 255) bsum[blockIdx.x] = s[255];
}
__global__ __launch_bounds__(64) void scanB(int* __restrict__ bsum, int nb){
  if (threadIdx.x == 0){
    int a = 0;
    for (int b = 0; b < nb; ++b){ int t = bsum[b]; bsum[b] = a; a += t; }
  }
}
__global__ __launch_bounds__(256) void scanC(const int* __restrict__ bsum, int* __restrict__ fill,
                                             int* __restrict__ row_ptr, int N){
  int i = blockIdx.x*256 + threadIdx.x;
  if (i < N){
    int st = fill[i] + bsum[i >> 8];
    fill[i] = st;
    row_ptr[i] = st;
  }
  if (i == 0) row_ptr[N] = N_EDGES;   // dst clamped -> every edge counted
}

__global__ __launch_bounds__(256) void fill_csr(const int* __restrict__ dst,
                                                int* __restrict__ fill, int* __restrict__ eids){
  int e = blockIdx.x*256 + threadIdx.x;
  if (e < N_EDGES){
    int p = atomicAdd(&fill[dst[e]], 1);
    eids[p] = e;
  }
}

// ---------------- GEMM: C[M][N] = A[M][K](lda) @ Bt[N][K] + bias ----------------
__global__ __launch_bounds__(256)
void gemm_bias(const bf16* __restrict__ A, int lda,
               const bf16* __restrict__ Bt,
               const bf16* __restrict__ bias, bf16* __restrict__ Cout, int ldc,
               int M, int N, int K)
{
  __shared__ bf16 As[128*64];
  __shared__ bf16 Bs[128*64];
  const int tid = threadIdx.x;
  const int lane = tid & 63;
  const int wave = tid >> 6;
  const int m0 = blockIdx.y * 128, n0 = blockIdx.x * 128;
  const int wm = (wave >> 1) * 64, wn = (wave & 1) * 64;
  const int l15 = lane & 15, l4 = lane >> 4;
  const int srow = lane >> 3;
  const int schunk = lane & 7;

  f32x4 acc[4][4] = {};

  for (int k0 = 0; k0 < K; k0 += 64){
    #pragma unroll
    for (int j = 0; j < 4; ++j){
      int r0 = (wave*4 + j)*8;
      int r  = r0 + srow;
      int gc = schunk ^ (r & 7);
      int ga = m0 + r; if (ga >= M) ga = M-1;
      gload_lds16(A  + (size_t)ga*lda      + k0 + gc*8, As + r0*64);
      gload_lds16(Bt + (size_t)(n0 + r)*K  + k0 + gc*8, Bs + r0*64);
    }
    __syncthreads();
    #pragma unroll
    for (int kt = 0; kt < 2; ++kt){
      bf16x8 af[4], bfr[4];
      #pragma unroll
      for (int mt = 0; mt < 4; ++mt){
        int row = wm + mt*16 + l15;
        int p = (kt*4 + l4) ^ (l15 & 7);
        af[mt] = *(const bf16x8*)(As + row*64 + p*8);
      }
      #pragma unroll
      for (int nt = 0; nt < 4; ++nt){
        int row = wn + nt*16 + l15;
        int p = (kt*4 + l4) ^ (l15 & 7);
        bfr[nt] = *(const bf16x8*)(Bs + row*64 + p*8);
      }
      #pragma unroll
      for (int mt = 0; mt < 4; ++mt)
        #pragma unroll
        for (int nt = 0; nt < 4; ++nt)
          acc[mt][nt] = __builtin_amdgcn_mfma_f32_16x16x32_bf16(af[mt], bfr[nt], acc[mt][nt], 0, 0, 0);
    }
    __syncthreads();
  }

  #pragma unroll
  for (int nt = 0; nt < 4; ++nt){
    int col = n0 + wn + nt*16 + l15;
    float bv = (float)bias[col];
    #pragma unroll
    for (int mt = 0; mt < 4; ++mt){
      int rbase = m0 + wm + mt*16 + l4*4;
      #pragma unroll
      for (int r = 0; r < 4; ++r){
        int row = rbase + r;
        if (row < M) Cout[(size_t)row*ldc + col] = (bf16)(acc[mt][nt][r] + bv);
      }
    }
  }
}

// ---------------- occupancy-tuned GEMM for the big z2 GEMM ----------------
// Same proven 128x128 structure, but:
//  - __launch_bounds__(256, 4): cap 128 regs/wave (64 acc-AGPR + ~55 VGPR
//    fit) -> 4 waves/SIMD -> ~4 blocks/CU co-resident (was ~144 regs -> 3/SIMD).
//    Wave-level overlap is what covers the per-K-step barrier drain.
//  - row-contiguous epilogue: 4 consecutive 32B stores per row (full-line
//    writes; nt-outer order caused 1.5x HBM write amplification, 124 vs 82 MB).
__global__ __launch_bounds__(256, 4)
void gemm_biasO(const bf16* __restrict__ A, int lda,
                const bf16* __restrict__ Bt,
                const bf16* __restrict__ bias, bf16* __restrict__ Cout, int ldc,
                int M, int N, int K)
{
  __shared__ bf16 As[128*64];
  __shared__ bf16 Bs[128*64];
  const int tid = threadIdx.x;
  const int lane = tid & 63;
  const int wave = tid >> 6;
  const int m0 = blockIdx.y * 128, n0 = blockIdx.x * 128;
  const int wm = (wave >> 1) * 64, wn = (wave & 1) * 64;
  const int l15 = lane & 15, l4 = lane >> 4;
  const int srow = lane >> 3;
  const int schunk = lane & 7;

  f32x4 acc[4][4] = {};

  for (int k0 = 0; k0 < K; k0 += 64){
    #pragma unroll
    for (int j = 0; j < 4; ++j){
      int r0 = (wave*4 + j)*8;
      int r  = r0 + srow;
      int gc = schunk ^ (r & 7);
      int ga = m0 + r; if (ga >= M) ga = M-1;
      gload_lds16(A  + (size_t)ga*lda      + k0 + gc*8, As + r0*64);
      gload_lds16(Bt + (size_t)(n0 + r)*K  + k0 + gc*8, Bs + r0*64);
    }
    __syncthreads();
    #pragma unroll
    for (int kt = 0; kt < 2; ++kt){
      bf16x8 af[4], bfr[4];
      #pragma unroll
      for (int mt = 0; mt < 4; ++mt){
        int row = wm + mt*16 + l15;
        int p = (kt*4 + l4) ^ (l15 & 7);
        af[mt] = *(const bf16x8*)(As + row*64 + p*8);
      }
      #pragma unroll
      for (int nt = 0; nt < 4; ++nt){
        int row = wn + nt*16 + l15;
        int p = (kt*4 + l4) ^ (l15 & 7);
        bfr[nt] = *(const bf16x8*)(Bs + row*64 + p*8);
      }
      #pragma unroll
      for (int mt = 0; mt < 4; ++mt)
        #pragma unroll
        for (int nt = 0; nt < 4; ++nt)
          acc[mt][nt] = __builtin_amdgcn_mfma_f32_16x16x32_bf16(af[mt], bfr[nt], acc[mt][nt], 0, 0, 0);
    }
    __syncthreads();
  }

  float bv[4];
  #pragma unroll
  for (int nt = 0; nt < 4; ++nt) bv[nt] = (float)bias[n0 + wn + nt*16 + l15];
  #pragma unroll
  for (int mt = 0; mt < 4; ++mt){
    int rbase = m0 + wm + mt*16 + l4*4;
    #pragma unroll
    for (int r = 0; r < 4; ++r){
      int row = rbase + r;
      if (row < M){
        #pragma unroll
        for (int nt = 0; nt < 4; ++nt)
          Cout[(size_t)row*ldc + n0 + wn + nt*16 + l15] = (bf16)(acc[mt][nt][r] + bv[nt]);
      }
    }
  }
}

// ---------------- deep-pipelined z-GEMM: BM=256 x BN=128, BK=64, 512 thr, 8 waves ----
// Triple-buffered LDS (144 KiB), staging issued 2 K-tiles ahead, counted
// s_waitcnt vmcnt(6) + raw s_barrier once per K-tile. Used for L3 (K=256).
__global__ __launch_bounds__(512, 1)
void gemm8p_bias(const bf16* __restrict__ A, int lda,
                 const bf16* __restrict__ Bt,
                 const bf16* __restrict__ bias, bf16* __restrict__ Cout, int ldc,
                 int M, int K)
{
  __shared__ bf16 As[3][256*64];
  __shared__ bf16 Bs[3][128*64];
  const int tid = threadIdx.x;
  const int lane = tid & 63;
  const int wave = tid >> 6;                 // 0..7
  const int m0 = blockIdx.y * 256, n0 = blockIdx.x * 128;
  const int wm = (wave >> 1) * 64;           // 4 m-waves x 64 rows
  const int wn = (wave & 1) * 64;            // 2 n-waves x 64 cols
  const int l15 = lane & 15, l4 = lane >> 4;
  const int srow = lane >> 3;                // 0..7
  const int schunk = lane & 7;               // 0..7
  const int NT = K >> 6;

  auto stageA = [&](int t, int j){
    int b = t % 3;
    int r0 = (wave + j*8)*8;
    int r  = r0 + srow;
    int gc = schunk ^ srow;
    int ga = m0 + r; if (ga >= M) ga = M-1;
    gload_lds16(A + (size_t)ga*lda + t*64 + gc*8, &As[b][r0*64]);
  };
  auto stageB = [&](int t, int j){
    int b = t % 3;
    int r0 = (wave + j*8)*8;
    int r  = r0 + srow;
    int gc = schunk ^ srow;
    gload_lds16(Bt + (size_t)(n0 + r)*K + t*64 + gc*8, &Bs[b][r0*64]);
  };

  stageA(0,0); stageA(0,1); stageA(0,2); stageA(0,3); stageB(0,0); stageB(0,1);
  if (NT > 1){ stageA(1,0); stageA(1,1); stageA(1,2); stageA(1,3); stageB(1,0); stageB(1,1); }
  if (NT > 1) asm volatile("s_waitcnt vmcnt(6)" ::: "memory");
  else        asm volatile("s_waitcnt vmcnt(0)" ::: "memory");
  __builtin_amdgcn_s_barrier();

  f32x4 acc[4][4] = {};

  for (int t = 0; t < NT; ++t){
    const bf16* as = &As[t % 3][0];
    const bf16* bs = &Bs[t % 3][0];
    bf16x8 bfr[4][2];
    bf16x8 af[2][2];

    #pragma unroll
    for (int nt2 = 0; nt2 < 4; ++nt2)
      #pragma unroll
      for (int kt = 0; kt < 2; ++kt){
        int row = wn + nt2*16 + l15;
        int p = (kt*4 + l4) ^ (l15 & 7);
        bfr[nt2][kt] = *(const bf16x8*)(bs + row*64 + p*8);
      }
    #pragma unroll
    for (int i = 0; i < 2; ++i)
      #pragma unroll
      for (int kt = 0; kt < 2; ++kt){
        int row = wm + i*16 + l15;
        int p = (kt*4 + l4) ^ (l15 & 7);
        af[i][kt] = *(const bf16x8*)(as + row*64 + p*8);
      }
    if (t + 2 < NT){ stageA(t+2,0); stageA(t+2,1); stageB(t+2,0); }
    __builtin_amdgcn_s_setprio(1);
    #pragma unroll
    for (int i = 0; i < 2; ++i)
      #pragma unroll
      for (int nt2 = 0; nt2 < 4; ++nt2)
        #pragma unroll
        for (int kt = 0; kt < 2; ++kt)
          acc[i][nt2] = __builtin_amdgcn_mfma_f32_16x16x32_bf16(af[i][kt], bfr[nt2][kt], acc[i][nt2], 0, 0, 0);
    __builtin_amdgcn_s_setprio(0);

    #pragma unroll
    for (int i = 0; i < 2; ++i)
      #pragma unroll
      for (int kt = 0; kt < 2; ++kt){
        int row = wm + (2+i)*16 + l15;
        int p = (kt*4 + l4) ^ (l15 & 7);
        af[i][kt] = *(const bf16x8*)(as + row*64 + p*8);
      }
    if (t + 2 < NT){ stageA(t+2,2); stageA(t+2,3); stageB(t+2,1); }
    __builtin_amdgcn_s_setprio(1);
    #pragma unroll
    for (int i = 0; i < 2; ++i)
      #pragma unroll
      for (int nt2 = 0; nt2 < 4; ++nt2)
        #pragma unroll
        for (int kt = 0; kt < 2; ++kt)
          acc[2+i][nt2] = __builtin_amdgcn_mfma_f32_16x16x32_bf16(af[i][kt], bfr[nt2][kt], acc[2+i][nt2], 0, 0, 0);
    __builtin_amdgcn_s_setprio(0);

    if (t < NT - 1){
      if (t + 2 < NT) asm volatile("s_waitcnt vmcnt(6)" ::: "memory");
      else            asm volatile("s_waitcnt vmcnt(0)" ::: "memory");
      __builtin_amdgcn_s_barrier();
    }
  }

  #pragma unroll
  for (int nt2 = 0; nt2 < 4; ++nt2){
    int col = n0 + wn + nt2*16 + l15;
    float bv = (float)bias[col];
    #pragma unroll
    for (int mt = 0; mt < 4; ++mt){
      int rbase = m0 + wm + mt*16 + l4*4;
      #pragma unroll
      for (int r = 0; r < 4; ++r){
        int row = rbase + r;
        if (row < M) Cout[(size_t)row*ldc + col] = (bf16)(acc[mt][nt2][r] + bv);
      }
    }
  }
}

// ---------------- fused PV-projection GEMM (replaces split-K + finalize) ----------------
// C-tile BM x 128, full K in one block: no atomics, no finalize pass.
// OUTMODE 0: out = ELU(acc + bp[col] - deg0*mb[col]) -> bf16 strided (next layer AP)
// OUTMODE 1: out = acc -> f32 linear (facc, N=128; finalize_gate consumes)
template<int BM, int OUTMODE>
__global__ __launch_bounds__(256)
void gemm_fused(const bf16* __restrict__ A, int lda,
                const bf16* __restrict__ Bt,
                const bf16* __restrict__ bp, const bf16* __restrict__ mb,
                const int* __restrict__ row_ptr,
                bf16* __restrict__ outB, int ldo, float* __restrict__ outF,
                int M, int K)
{
  constexpr int PA    = BM/32;      // A staging passes (4 waves x 8 rows each)
  constexpr int WCOLS = 128/BM;     // waves along N (wave grid: (BM/32) x WCOLS)
  constexpr int WTN   = BM;         // wave tile N = 128/WCOLS
  constexpr int NT    = WTN/16;
  __shared__ bf16 As[BM*64];
  __shared__ bf16 Bs[128*64];
  const int tid = threadIdx.x;
  const int lane = tid & 63;
  const int wave = tid >> 6;
  const int m0 = blockIdx.y * BM, n0 = blockIdx.x * 128;
  const int wm = (wave / WCOLS) * 32;
  const int wn = (wave % WCOLS) * WTN;
  const int l15 = lane & 15, l4 = lane >> 4;
  const int srow = lane >> 3;
  const int schunk = lane & 7;

  f32x4 acc[2][NT] = {};

  for (int k0 = 0; k0 < K; k0 += 64){
    #pragma unroll
    for (int j = 0; j < PA; ++j){
      int r0 = (wave*PA + j)*8;
      int r  = r0 + srow;
      int gc = schunk ^ (r & 7);
      int ga = m0 + r; if (ga >= M) ga = M-1;
      gload_lds16(A + (size_t)ga*lda + k0 + gc*8, As + r0*64);
    }
    #pragma unroll
    for (int j = 0; j < 4; ++j){
      int r0 = (wave*4 + j)*8;
      int r  = r0 + srow;
      int gc = schunk ^ (r & 7);
      gload_lds16(Bt + (size_t)(n0 + r)*K + k0 + gc*8, Bs + r0*64);
    }
    __syncthreads();
    #pragma unroll
    for (int kt = 0; kt < 2; ++kt){
      bf16x8 af[2], bfr[NT];
      #pragma unroll
      for (int mt = 0; mt < 2; ++mt){
        int row = wm + mt*16 + l15;
        int p = (kt*4 + l4) ^ (l15 & 7);
        af[mt] = *(const bf16x8*)(As + row*64 + p*8);
      }
      #pragma unroll
      for (int nt = 0; nt < NT; ++nt){
        int row = wn + nt*16 + l15;
        int p = (kt*4 + l4) ^ (l15 & 7);
        bfr[nt] = *(const bf16x8*)(Bs + row*64 + p*8);
      }
      #pragma unroll
      for (int mt = 0; mt < 2; ++mt)
        #pragma unroll
        for (int nt = 0; nt < NT; ++nt)
          acc[mt][nt] = __builtin_amdgcn_mfma_f32_16x16x32_bf16(af[mt], bfr[nt], acc[mt][nt], 0, 0, 0);
    }
    __syncthreads();
  }

  if (OUTMODE == 0){
    float bv[NT], mv[NT];
    #pragma unroll
    for (int nt = 0; nt < NT; ++nt){
      int col = n0 + wn + nt*16 + l15;
      bv[nt] = (float)bp[col];
      mv[nt] = (float)mb[col];
    }
    #pragma unroll
    for (int mt = 0; mt < 2; ++mt){
      int rbase = m0 + wm + mt*16 + l4*4;
      #pragma unroll
      for (int r = 0; r < 4; ++r){
        int row = rbase + r;
        if (row < M){
          bool d0 = (row_ptr[row+1] == row_ptr[row]);
          #pragma unroll
          for (int nt = 0; nt < NT; ++nt){
            int col = n0 + wn + nt*16 + l15;
            float v = acc[mt][nt][r] + bv[nt] - (d0 ? mv[nt] : 0.f);
            v = (v > 0.f) ? v : (__expf(v) - 1.f);
            outB[(size_t)row*ldo + col] = (bf16)v;
          }
        }
      }
    }
  } else {
    #pragma unroll
    for (int mt = 0; mt < 2; ++mt){
      int rbase = m0 + wm + mt*16 + l4*4;
      #pragma unroll
      for (int r = 0; r < 4; ++r){
        int row = rbase + r;
        if (row < M){
          #pragma unroll
          for (int nt = 0; nt < NT; ++nt){
            int col = n0 + wn + nt*16 + l15;
            outF[(size_t)row*128 + col] = acc[mt][nt][r];
          }
        }
      }
    }
  }
}

// ---------------- L3 finalize fused with gate computation (NO atomics) ----------------
// block = 256 threads = 2 rows of 128; writes h3 and gate[n] only.
__global__ __launch_bounds__(256)
void finalize_gate(const float* __restrict__ facc, const bf16* __restrict__ bp,
                   const bf16* __restrict__ mb, const int* __restrict__ row_ptr,
                   bf16* __restrict__ hout, const bf16* __restrict__ wg,
                   const bf16* __restrict__ bg, float* __restrict__ gate)
{
  __shared__ float wred[4];
  int idx = blockIdx.x*256 + threadIdx.x;     // < N_NODES*128
  int n = idx >> 7, c = idx & 127;
  bool d0 = (row_ptr[n+1] == row_ptr[n]);
  float v = facc[idx] + (float)bp[c] - (d0 ? (float)mb[c] : 0.f);
  v = (v > 0.f) ? v : (__expf(v) - 1.f);
  hout[idx] = (bf16)v;
  float gc = v * (float)wg[c];
  #pragma unroll
  for (int o = 32; o; o >>= 1) gc += __shfl_xor(gc, o, 64);
  int wave = threadIdx.x >> 6;
  if ((threadIdx.x & 63) == 0) wred[wave] = gc;
  __syncthreads();
  if ((threadIdx.x & 127) == 0){
    float g = wred[wave] + wred[wave + 1] + (float)bg[0];
    gate[n] = g;
  }
}

// ---------------- atomic-free segmented softmax-pool (batch is sorted) ----------------
__global__ __launch_bounds__(256)
void pool_graphs(const float* __restrict__ gate, const int* __restrict__ bat,
                 const bf16* __restrict__ h, float* __restrict__ gacc)
{
  int b = blockIdx.x;
  int lo = 0, hi = N_NODES;
  while (lo < hi){ int mid = (lo + hi) >> 1; if (bat[mid] < b) lo = mid + 1; else hi = mid; }
  int s = lo;
  lo = s; hi = N_NODES;
  while (lo < hi){ int mid = (lo + hi) >> 1; if (bat[mid] < b + 1) lo = mid + 1; else hi = mid; }
  int e = lo;

  int t = threadIdx.x;
  float m = -3.4e38f;
  for (int n = s + t; n < e; n += 256) m = fmaxf(m, gate[n]);
  #pragma unroll
  for (int o = 32; o; o >>= 1) m = fmaxf(m, __shfl_xor(m, o, 64));
  __shared__ float red[4];
  int wv = t >> 6;
  if ((t & 63) == 0) red[wv] = m;
  __syncthreads();
  m = fmaxf(fmaxf(red[0], red[1]), fmaxf(red[2], red[3]));

  int team = t >> 7, c = t & 127;
  float acc = 0.f, se = 0.f;
  for (int n = s + team; n < e; n += 2){
    float en = __expf(gate[n] - m);
    acc += en * (float)h[(size_t)n*128 + c];
    if (c == 0) se += en;
  }
  __shared__ float accs[256];
  __shared__ float ses[2];
  accs[t] = acc;
  if (c == 0) ses[team] = se;
  __syncthreads();
  if (t < 128){
    float tot = accs[t] + accs[128 + t];
    float S = ses[0] + ses[1];
    gacc[b*128 + t] = tot / (S + 1e-16f);
  }
}

// ---------------- merged M_h precompute (all 3 layers, 1 dispatch) ----------------
struct MhPack { const bf16* wk[3]; const bf16* wq[3]; bf16* wzt[3]; int fin[3]; int c[3]; };
__global__ __launch_bounds__(256)
void gemm_mh_all(MhPack P)
{
  const int L = blockIdx.z >> 3, h = blockIdx.z & 7;
  const int Fin = P.fin[L], C = P.c[L];
  const int nb = Fin >> 7;
  if ((int)blockIdx.x >= nb || (int)blockIdx.y >= nb) return;
  __shared__ bf16 As[128*64];
  __shared__ bf16 Bs[128*64];
  const int ld = 8*C;
  const bf16* Ab = P.wk[L] + h*C;
  const bf16* Bb = P.wq[L] + h*C;
  bf16* Cb = P.wzt[L] + (size_t)h*Fin*Fin;
  const int tid = threadIdx.x;
  const int lane = tid & 63;
  const int wave = tid >> 6;
  const int m0 = blockIdx.y * 128, n0 = blockIdx.x * 128;
  const int wm = (wave >> 1) * 64, wn = (wave & 1) * 64;
  const int l15 = lane & 15, l4 = lane >> 4;
  const int srow = lane >> 3;
  const int schunk = lane & 7;

  f32x4 acc[4][4] = {};

  for (int k0 = 0; k0 < C; k0 += 64){
    #pragma unroll
    for (int j = 0; j < 4; ++j){
      int r0 = (wave*4 + j)*8;
      int r  = r0 + srow;
      int gc = schunk ^ (r & 7);
      gload_lds16(Ab + (size_t)(m0 + r)*ld + k0 + gc*8, As + r0*64);
      gload_lds16(Bb + (size_t)(n0 + r)*ld + k0 + gc*8, Bs + r0*64);
    }
    __syncthreads();
    #pragma unroll
    for (int kt = 0; kt < 2; ++kt){
      bf16x8 af[4], bfr[4];
      #pragma unroll
      for (int mt = 0; mt < 4; ++mt){
        int row = wm + mt*16 + l15;
        int p = (kt*4 + l4) ^ (l15 & 7);
        af[mt] = *(const bf16x8*)(As + row*64 + p*8);
      }
      #pragma unroll
      for (int nt = 0; nt < 4; ++nt){
        int row = wn + nt*16 + l15;
        int p = (kt*4 + l4) ^ (l15 & 7);
        bfr[nt] = *(const bf16x8*)(Bs + row*64 + p*8);
      }
      #pragma unroll
      for (int mt = 0; mt < 4; ++mt)
        #pragma unroll
        for (int nt = 0; nt < 4; ++nt)
          acc[mt][nt] = __builtin_amdgcn_mfma_f32_16x16x32_bf16(af[mt], bfr[nt], acc[mt][nt], 0, 0, 0);
    }
    __syncthreads();
  }

  #pragma unroll
  for (int nt = 0; nt < 4; ++nt){
    int col = n0 + wn + nt*16 + l15;
    #pragma unroll
    for (int mt = 0; mt < 4; ++mt){
      int rbase = m0 + wm + mt*16 + l4*4;
      #pragma unroll
      for (int r = 0; r < 4; ++r)
        Cb[(size_t)(rbase + r)*Fin + col] = (bf16)acc[mt][nt][r];
    }
  }
}

// ---------------- merged Wv/Ws prep (all 3 layers) ----------------
struct WvPack { const void* wv[3]; const void* ws[3]; bf16* bt[3]; int fin[3]; int c[3]; int bx[3]; int by[3]; };
__global__ __launch_bounds__(256)
void prep_wv_all(WvPack P, const int* __restrict__ flagF)
{
  const int L = blockIdx.z;
  if ((int)blockIdx.x >= P.bx[L] || (int)blockIdx.y >= P.by[L]) return;
  __shared__ float t[32][33];
  bool f = (*flagF != 0);
  const int Fin = P.fin[L], C = P.c[L];
  int k0 = blockIdx.x*32, j0 = blockIdx.y*32;
  int x = threadIdx.x & 31, y = threadIdx.x >> 5;
  const void* srcp; int nstride, cb; float sc; int i0;
  if (k0 < 8*Fin){
    int h = k0 / Fin; i0 = k0 - h*Fin;
    srcp = P.wv[L]; nstride = 8*C; cb = h*C + j0; sc = 0.125f;
  } else {
    i0 = k0 - 8*Fin;
    srcp = P.ws[L]; nstride = C; cb = j0; sc = 1.0f;
  }
  #pragma unroll
  for (int ii = 0; ii < 4; ++ii){
    int i = i0 + y + ii*8;
    size_t idx = (size_t)i*nstride + cb + x;
    float v = f ? ((const float*)srcp)[idx] : (float)((const bf16*)srcp)[idx];
    t[y + ii*8][x] = v*sc;
  }
  __syncthreads();
  #pragma unroll
  for (int ii = 0; ii < 4; ++ii){
    int j = j0 + y + ii*8;
    P.bt[L][(size_t)j*(9*Fin) + k0 + x] = (bf16)t[x][y + ii*8];
  }
}

// ---------------- merged small prep (all 3 layers), wave-per-row ----------------
struct SmPack { const bf16* wkc[3]; const void* bq[3]; const void* bv[3]; const void* bs[3];
                int fin[3]; int c[3]; bf16* tz[3]; bf16* bp[3]; bf16* mb[3]; int rb[3]; int bpb[3]; };
__global__ __launch_bounds__(256)
void prep_small_all(SmPack P, const int* __restrict__ flagF)
{
  const int L = blockIdx.z;
  const int Fin = P.fin[L], C = P.c[L];
  const int rb = P.rb[L];
  if ((int)blockIdx.x >= rb + P.bpb[L]) return;
  bool f = (*flagF != 0);
  if ((int)blockIdx.x < rb){
    int wave = threadIdx.x >> 6, lane = threadIdx.x & 63;
    int r = blockIdx.x*4 + wave;            // r < 8*Fin (rb = 8*Fin/4)
    int h = r / Fin, i = r - h*Fin;
    int epc = C >> 6;
    const bf16* wp = P.wkc[L] + (size_t)i*8*C + h*C;
    const void* bqp = P.bq[L];
    float s = 0.f;
    for (int k = 0; k < epc; ++k){
      int c = k*64 + lane;
      float b = f ? ((const float*)bqp)[h*C + c] : (float)((const bf16*)bqp)[h*C + c];
      s += (float)wp[c] * b;
    }
    #pragma unroll
    for (int o = 32; o; o >>= 1) s += __shfl_xor(s, o, 64);
    if (lane == 0) P.tz[L][r] = (bf16)s;
  } else {
    int idx = ((int)blockIdx.x - rb)*256 + threadIdx.x;
    if (idx < C){
      float s = 0.f;
      for (int h = 0; h < 8; ++h)
        s += f ? ((const float*)P.bv[L])[h*C + idx] : (float)((const bf16*)P.bv[L])[h*C + idx];
      s *= 0.125f;
      float bsv = f ? ((const float*)P.bs[L])[idx] : (float)((const bf16*)P.bs[L])[idx];
      P.mb[L][idx] = (bf16)s;
      P.bp[L][idx] = (bf16)(s + bsv);
    }
  }
}

// ---------------- edge phase, wave-per-node rewrite ----------------
// One wave owns one node (4 nodes/block, no barriers).
// Scores via MFMA 16x16x32 bf16; softmax all heads at once; PV scalar with
// alpha in LDS, 4-edge prefetch batches, packed f32x2 FMA.
// deg capped at 64 (Poisson(8) over 10k nodes: max ~24; P(>64) ~ 1e-40).
template<int Fin, int NHT>
__global__ __launch_bounds__(256)
void node_edge(const bf16* __restrict__ z, int zw, int hbase,
               bf16* __restrict__ AP, int ldP,
               const int* __restrict__ row_ptr, const int* __restrict__ eids,
               const int* __restrict__ srcv, float scale)
{
  constexpr int EPL  = Fin/64;   // elems/lane for full-row ops
  constexpr int EPL2 = EPL/2;    // f32x2 pairs/lane
  constexpr int KC   = Fin/32;   // mfma k-steps
  typedef typename VecT<EPL>::type vecb;
  __shared__ float sw[4][68][12];   // [wave][edge][head] alpha; 12-col pad for 16B-aligned rows

  const int wave = threadIdx.x >> 6;
  const int lane = threadIdx.x & 63;
  const int n = blockIdx.x*4 + wave;            // grid*4 == N_NODES exactly

  const int beg = row_ptr[n];
  int deg = row_ptr[n+1] - beg;
  if (deg > 64) deg = 64;

  bf16* APn = AP + (size_t)n*ldP;

  if (deg == 0){
    vecb zv;
    #pragma unroll
    for (int k = 0; k < EPL; ++k) zv[k] = (bf16)0.f;
    #pragma unroll
    for (int h = 0; h < NHT; ++h)
      *(vecb*)(APn + (size_t)(hbase + h)*Fin + lane*EPL) = zv;
    return;
  }

  // per-lane src node index (clamped so every lane holds a valid index)
  int e_ld = (lane < deg) ? lane : 0;
  int srcReg = srcv[eids[beg + e_ld]];

  const int nc = (deg + 15) >> 4;               // 16-edge chunks, <=4
  const int l15 = lane & 15, l4 = lane >> 4;
  const int h   = l15 & (NHT-1);
  const bf16* zp = z + (size_t)n*zw + (size_t)h*Fin + l4*8;

  // ---- scores via MFMA ----
  f32x4 sacc[4];
  #pragma unroll
  for (int c = 0; c < 4; ++c) sacc[c] = (f32x4){0.f,0.f,0.f,0.f};

  #pragma unroll
  for (int c = 0; c < 4; ++c){
    if (c < nc){
      int sn = __shfl(srcReg, c*16 + l15, 64);  // edge for this lane's A-row
      const bf16* ap = AP + (size_t)sn*ldP + 8*Fin + l4*8;
      f32x4 s = (f32x4){0.f,0.f,0.f,0.f};
      #pragma unroll
      for (int k = 0; k < KC; ++k){
        bf16x8 af = *(const bf16x8*)(ap + k*32);
        bf16x8 bv = *(const bf16x8*)(zp + k*32);
        s = __builtin_amdgcn_mfma_f32_16x16x32_bf16(af, bv, s, 0, 0, 0);
      }
      sacc[c] = s;
    }
  }

  // ---- softmax over edges, all heads at once (col = l15 = head) ----
  float m = -3.4e38f;
  #pragma unroll
  for (int c = 0; c < 4; ++c){
    if (c < nc){
      #pragma unroll
      for (int r = 0; r < 4; ++r){
        int row = c*16 + l4*4 + r;
        float v = sacc[c][r]*scale;
        sacc[c][r] = v;
        if (row < deg) m = fmaxf(m, v);
      }
    }
  }
  m = fmaxf(m, __shfl_xor(m, 16, 64));
  m = fmaxf(m, __shfl_xor(m, 32, 64));
  float ssum = 0.f;
  #pragma unroll
  for (int c = 0; c < 4; ++c){
    if (c < nc){
      #pragma unroll
      for (int r = 0; r < 4; ++r){
        int row = c*16 + l4*4 + r;
        float e = (row < deg) ? __expf(sacc[c][r] - m) : 0.f;
        sacc[c][r] = e;
        ssum += e;
      }
    }
  }
  ssum += __shfl_xor(ssum, 16, 64);
  ssum += __shfl_xor(ssum, 32, 64);
  float inv = 1.f/(ssum + 1e-16f);

  if (l15 < NHT){
    #pragma unroll
    for (int c = 0; c < 4; ++c){
      if (c < nc){
        #pragma unroll
        for (int r = 0; r < 4; ++r)
          sw[wave][c*16 + l4*4 + r][l15] = sacc[c][r]*inv;
      }
    }
  }
  // zero the 4 pad rows past the last chunk (PV batches may overrun by <=3)
  if (lane < 4*NHT)
    sw[wave][nc*16 + (lane >> 3)][lane & 7] = 0.f;
  // same-wave LDS write->read: compiler inserts lgkmcnt; no barrier needed

  // ---- PV: P[h] = sum_e alpha[e][h] * x_src[e], x read once, 4-edge batches ----
  f32x2 acc[NHT][EPL2];
  #pragma unroll
  for (int hh = 0; hh < NHT; ++hh)
    #pragma unroll
    for (int p = 0; p < EPL2; ++p) acc[hh][p] = (f32x2){0.f,0.f};

  for (int i0 = 0; i0 < deg; i0 += 4){
    int sn0 = __shfl(srcReg, i0,   64);
    int sn1 = __shfl(srcReg, i0+1, 64);   // >=deg -> alpha 0; wraps >=64 -> valid idx
    int sn2 = __shfl(srcReg, i0+2, 64);
    int sn3 = __shfl(srcReg, i0+3, 64);
    vecb hv0 = *(const vecb*)(AP + (size_t)sn0*ldP + 8*Fin + lane*EPL);
    vecb hv1 = *(const vecb*)(AP + (size_t)sn1*ldP + 8*Fin + lane*EPL);
    vecb hv2 = *(const vecb*)(AP + (size_t)sn2*ldP + 8*Fin + lane*EPL);
    vecb hv3 = *(const vecb*)(AP + (size_t)sn3*ldP + 8*Fin + lane*EPL);
    #pragma unroll
    for (int j = 0; j < 4; ++j){
      int e = i0 + j;
      vecb hv = (j == 0) ? hv0 : (j == 1) ? hv1 : (j == 2) ? hv2 : hv3;
      f32x4 w0 = *(const f32x4*)&sw[wave][e][0];
      f32x4 w1 = (NHT == 8) ? *(const f32x4*)&sw[wave][e][4] : w0;
      f32x2 xf[EPL2];
      const u32* up = (const u32*)&hv;
      #pragma unroll
      for (int p = 0; p < EPL2; ++p){
        u32 u = up[p];
        xf[p] = (f32x2){ __uint_as_float(u << 16), __uint_as_float(u & 0xffff0000u) };
      }
      #pragma unroll
      for (int hh = 0; hh < NHT; ++hh){
        float w = (hh < 4) ? w0[hh] : w1[hh-4];
        f32x2 wv = (f32x2){w, w};
        #pragma unroll
        for (int p = 0; p < EPL2; ++p)
          acc[hh][p] += wv * xf[p];
      }
    }
  }

  #pragma unroll
  for (int hh = 0; hh < NHT; ++hh){
    vecb o;
    #pragma unroll
    for (int p = 0; p < EPL2; ++p){
      o[2*p]   = (bf16)acc[hh][p][0];
      o[2*p+1] = (bf16)acc[hh][p][1];
    }
    *(vecb*)(APn + (size_t)(hbase + hh)*Fin + lane*EPL) = o;
  }
}

__global__ __launch_bounds__(64) void final_fc(const float* __restrict__ gacc, const bf16* __restrict__ wfc,
                                               const bf16* __restrict__ bfc, void* __restrict__ out,
                                               const int* __restrict__ flagF){
  int g = blockIdx.x;
  int o = threadIdx.x;
  if (o < 10){
    float s = (float)bfc[o];
    for (int c = 0; c < 128; ++c) s += gacc[g*128 + c]*(float)wfc[c*10 + o];
    if (*flagF) ((float*)out)[(size_t)g*10 + o] = s;
    else        ((bf16*)out)[(size_t)g*10 + o]  = (bf16)s;
  }
}

extern "C" void kernel_launch(void* const* d_in, const int* in_sizes, int n_in,
                              void* d_out, int out_size, void* d_ws, size_t ws_size,
                              hipStream_t stream)
{
  const int* ei   = (const int*)d_in[1];
  const int* braw = (const int*)d_in[2];

  // ---- workspace plan (arena-aliased); adaptive A2 size for one-shot layer-2 ----
  bf16 *Wzt1=0,*Wzt2=0,*Wzt3=0,*Wvt1=0,*Wvt2=0,*Wvt3=0;
  float *facc=0,*gate=0;
  bf16 *tz1=0,*tz2=0,*tz3=0,*bp1=0,*mb1=0,*bp2=0,*mb2=0,*bp3=0,*mb3=0,*h3=0;
  bf16 *cwg=0,*cbg=0,*cwfc=0,*cbfc=0;
  int *src=0,*dst=0,*bat=0,*cnt=0,*row_ptr=0,*fillp=0,*eids=0,*flagbuf=0;
  char *A1=0, *A2=0;

  auto plan = [&](bool big)->size_t{
    size_t off = 0;
    auto A = [&](size_t bytes)->char*{
      char* p = (char*)d_ws + off;
      off += (bytes + 255) & ~(size_t)255;
      return p;
    };
    A1 = A(92160000);
    A2 = A(big ? 81920000 : 46080000);
    Wzt1 = (bf16*)A((size_t)8*128*128*2);
    Wzt2 = (bf16*)A((size_t)8*512*512*2);
    Wzt3 = (bf16*)A((size_t)8*256*256*2);
    Wvt1 = (bf16*)A((size_t)512*9*128*2);
    Wvt2 = (bf16*)A((size_t)256*9*512*2);
    Wvt3 = (bf16*)A((size_t)128*9*256*2);
    facc = (float*)A((size_t)N_NODES*512*4);
    tz1  = (bf16*)A(8*128*2);
    tz2  = (bf16*)A(8*512*2);
    tz3  = (bf16*)A(8*256*2);
    bp1  = (bf16*)A(512*2);  mb1 = (bf16*)A(512*2);
    bp2  = (bf16*)A(256*2);  mb2 = (bf16*)A(256*2);
    bp3  = (bf16*)A(128*2);  mb3 = (bf16*)A(128*2);
    h3   = (bf16*)A((size_t)N_NODES*128*2);
    src  = (int*)A((size_t)N_EDGES*4);
    dst  = (int*)A((size_t)N_EDGES*4);
    bat  = (int*)A((size_t)N_NODES*4);
    cnt  = (int*)A((size_t)N_NODES*4);
    row_ptr = (int*)A((size_t)(N_NODES+1)*4);
    fillp= (int*)A((size_t)N_NODES*4);
    eids = (int*)A((size_t)N_EDGES*4);
    flagbuf = (int*)A(16384);
    gate = (float*)A((size_t)N_NODES*4);
    unsigned* poolz = (unsigned*)A((size_t)(64 + 64 + 64*128)*4);
    (void)poolz;
    cwg  = (bf16*)A(128*2);
    cbg  = (bf16*)A(2*2);
    cwfc = (bf16*)A(1280*2);
    cbfc = (bf16*)A(10*2);
    return off;
  };

  bool big = (plan(true) <= ws_size);
  if (!big && plan(false) > ws_size) return;   // floor plan doesn't fit; visible failure
  plan(big);
  unsigned* poolz = (unsigned*)((char*)gate + (((size_t)N_NODES*4 + 255) & ~(size_t)255));

  int* flagI = flagbuf;
  int* flagF = flagbuf + 1;
  int* bsum  = (int*)((char*)flagbuf + 8192);
  float*    gacc = (float*)(poolz + 128);

  bf16* AP1 = (bf16*)A2;   const int ldP1 = 1152;   // [P(1024)|x(128)]
  bf16* z1  = (bf16*)A1;
  bf16* AP2 = (bf16*)A1;   const int ldP2 = 4608;   // [P(4096)|h1(512)]
  bf16* z2  = (bf16*)A2;                            // group (2048w) or big (4096w)
  bf16* AP3 = (bf16*)A2;   const int ldP3 = 2304;   // [P(2048)|h2(256)]
  bf16* z3  = (bf16*)A1;
  bf16* wq1c = (bf16*)(A1 + 48000000);  bf16* wk1c = wq1c + 128*4096;
  bf16* wq2c = wk1c + 128*4096;         bf16* wk2c = wq2c + 512*2048;
  bf16* wq3c = wk2c + 512*2048;         bf16* wk3c = wq3c + 256*1024;

  // ---- detection ----
  hipMemsetAsync(flagbuf, 0, 16384, stream);
  {
    int nprobe = in_sizes[0] < 32768 ? in_sizes[0] : 32768;
    detect_f32_k<<<(nprobe + 255)/256, 256, 0, stream>>>((const unsigned short*)d_in[0], nprobe, flagF);
    detect_i64<<<16, 256, 0, stream>>>(ei, flagI);
  }

  // ---- batched conversion ----
  {
    CvPack p;
    const int CIDX[11] = {0, 3, 5, 11, 13, 19, 21, 27, 28, 29, 30};
    bf16* CDST[11] = {AP1 + 1024, wq1c, wk1c, wq2c, wk2c, wq3c, wk3c, cwg, cbg, cwfc, cbfc};
    int tot = 0;
    for (int t = 0; t < 11; ++t){
      p.src[t] = d_in[CIDX[t]];
      p.dst[t] = CDST[t];
      p.pre[t] = tot;
      int n = in_sizes[CIDX[t]];
      tot += n;
      if (t == 0){ p.rl[t] = 128; p.st[t] = 1152; }
      else       { p.rl[t] = n;   p.st[t] = n;    }
    }
    p.pre[11] = tot;
    convert_all<<<(tot + 255)/256, 256, 0, stream>>>(p, flagF);
  }

  // ---- indices + CSR (parallel scan) ----
  hipMemsetAsync(cnt, 0, (size_t)N_NODES*4, stream);
  conv_idx<<<(N_EDGES + 255)/256, 256, 0, stream>>>(ei, braw, flagI, src, dst, bat, cnt);
  scanA<<<40, 256, 0, stream>>>(cnt, fillp, bsum, N_NODES);
  scanB<<<1, 64, 0, stream>>>(bsum, 40);
  scanC<<<40, 256, 0, stream>>>(bsum, fillp, row_ptr, N_NODES);
  fill_csr<<<(N_EDGES + 255)/256, 256, 0, stream>>>(dst, fillp, eids);

  // ---- merged setup ----
  {
    MhPack mp;
    mp.wk[0]=wk1c; mp.wk[1]=wk2c; mp.wk[2]=wk3c;
    mp.wq[0]=wq1c; mp.wq[1]=wq2c; mp.wq[2]=wq3c;
    mp.wzt[0]=Wzt1; mp.wzt[1]=Wzt2; mp.wzt[2]=Wzt3;
    mp.fin[0]=128; mp.fin[1]=512; mp.fin[2]=256;
    mp.c[0]=512; mp.c[1]=256; mp.c[2]=128;
    gemm_mh_all<<<dim3(4,4,24), 256, 0, stream>>>(mp);

    WvPack wp;
    wp.wv[0]=d_in[7];  wp.wv[1]=d_in[15]; wp.wv[2]=d_in[23];
    wp.ws[0]=d_in[9];  wp.ws[1]=d_in[17]; wp.ws[2]=d_in[25];
    wp.bt[0]=Wvt1; wp.bt[1]=Wvt2; wp.bt[2]=Wvt3;
    wp.fin[0]=128; wp.fin[1]=512; wp.fin[2]=256;
    wp.c[0]=512; wp.c[1]=256; wp.c[2]=128;
    wp.bx[0]=36; wp.bx[1]=144; wp.bx[2]=72;
    wp.by[0]=16; wp.by[1]=8;   wp.by[2]=4;
    prep_wv_all<<<dim3(144,16,3), 256, 0, stream>>>(wp, flagF);

    SmPack sp;
    sp.wkc[0]=wk1c; sp.wkc[1]=wk2c; sp.wkc[2]=wk3c;
    sp.bq[0]=d_in[4];  sp.bq[1]=d_in[12]; sp.bq[2]=d_in[20];
    sp.bv[0]=d_in[8];  sp.bv[1]=d_in[16]; sp.bv[2]=d_in[24];
    sp.bs[0]=d_in[10]; sp.bs[1]=d_in[18]; sp.bs[2]=d_in[26];
    sp.fin[0]=128; sp.fin[1]=512; sp.fin[2]=256;
    sp.c[0]=512; sp.c[1]=256; sp.c[2]=128;
    sp.tz[0]=tz1; sp.tz[1]=tz2; sp.tz[2]=tz3;
    sp.bp[0]=bp1; sp.bp[1]=bp2; sp.bp[2]=bp3;
    sp.mb[0]=mb1; sp.mb[1]=mb2; sp.mb[2]=mb3;
    sp.rb[0]=256;  sp.rb[1]=1024; sp.rb[2]=512;   // 8*Fin/4
    sp.bpb[0]=2;   sp.bpb[1]=1;   sp.bpb[2]=1;    // ceil(C/256)
    prep_small_all<<<dim3(1025,1,3), 256, 0, stream>>>(sp, flagF);
  }

  const int MT = (N_NODES + 127)/128;   // 79
  const int NB = N_NODES/4;             // node_edge: 4 nodes per block (wave-per-node)
  const int MT32 = (N_NODES + 31)/32;   // 313
  const int MT64 = (N_NODES + 63)/64;   // 157
  const int MT256 = (N_NODES + 255)/256; // 40
  const float sc1 = 1.0f/sqrtf(512.f), sc2 = 1.0f/sqrtf(256.f), sc3 = 1.0f/sqrtf(128.f);

  // ================= layer 1 (Fin=128, C=512) =================
  gemm_bias<<<dim3(8, MT), 256, 0, stream>>>(AP1 + 1024, ldP1, Wzt1, tz1, z1, 1024, N_NODES, 1024, 128);
  node_edge<128,8><<<NB, 256, 0, stream>>>(z1, 1024, 0, AP1, ldP1, row_ptr, eids, src, sc1);
  gemm_fused<64,0><<<dim3(4, MT64), 256, 0, stream>>>(AP1, ldP1, Wvt1, bp1, mb1, row_ptr,
                                                      AP2 + 4096, ldP2, (float*)0, N_NODES, 1152);

  // ================= layer 2 (Fin=512, C=256) =================
  if (big){
    gemm_biasO<<<dim3(32, MT), 256, 0, stream>>>(AP2 + 4096, ldP2, Wzt2, tz2, z2, 4096, N_NODES, 4096, 512);
    node_edge<512,8><<<NB, 256, 0, stream>>>(z2, 4096, 0, AP2, ldP2, row_ptr, eids, src, sc2);
  } else {
    for (int g = 0; g < 2; ++g){
      gemm_bias<<<dim3(16, MT), 256, 0, stream>>>(AP2 + 4096, ldP2, Wzt2 + (size_t)g*4*512*512, tz2 + g*4*512, z2, 2048, N_NODES, 2048, 512);
      node_edge<512,4><<<NB, 256, 0, stream>>>(z2, 2048, g*4, AP2, ldP2, row_ptr, eids, src, sc2);
    }
  }
  gemm_fused<64,0><<<dim3(2, MT64), 256, 0, stream>>>(AP2, ldP2, Wvt2, bp2, mb2, row_ptr,
                                                      AP3 + 2048, ldP3, (float*)0, N_NODES, 4608);

  // ================= layer 3 (Fin=256, C=128) =================
  gemm8p_bias<<<dim3(16, MT256), 512, 0, stream>>>(AP3 + 2048, ldP3, Wzt3, tz3, z3, 2048, N_NODES, 256);
  node_edge<256,8><<<NB, 256, 0, stream>>>(z3, 2048, 0, AP3, ldP3, row_ptr, eids, src, sc3);
  gemm_fused<32,1><<<dim3(1, MT32), 256, 0, stream>>>(AP3, ldP3, Wvt3, (const bf16*)0, (const bf16*)0, (const int*)0,
                                                      (bf16*)0, 0, facc, N_NODES, 2304);
  finalize_gate<<<(N_NODES*128)/256, 256, 0, stream>>>(facc, bp3, mb3, row_ptr, h3, cwg, cbg, gate);

  // ---- atomic-free global attention pooling + fc ----
  pool_graphs<<<N_GRAPHS, 256, 0, stream>>>(gate, bat, h3, gacc);
  final_fc<<<N_GRAPHS, 64, 0, stream>>>(gacc, cwfc, cbfc, d_out, flagF);
}

// Round 7
// 525.853 us; speedup vs baseline: 1.0694x; 1.0694x over previous
//
#include <hip/hip_runtime.h>
#include <math.h>

typedef __bf16 bf16;
typedef __bf16 bf16x8 __attribute__((ext_vector_type(8)));
typedef __bf16 bf16x4 __attribute__((ext_vector_type(4)));
typedef __bf16 bf16x2 __attribute__((ext_vector_type(2)));
typedef float f32x4 __attribute__((ext_vector_type(4)));
typedef float f32x2 __attribute__((ext_vector_type(2)));
typedef unsigned int u32;

#define N_NODES 10000
#define N_EDGES 80000
#define N_GRAPHS 64

template<int EPL> struct VecT;
template<> struct VecT<8>{ typedef bf16x8 type; };
template<> struct VecT<4>{ typedef bf16x4 type; };
template<> struct VecT<2>{ typedef bf16x2 type; };

__device__ inline void gload_lds16(const bf16* g, bf16* l){
  __builtin_amdgcn_global_load_lds(
      (const __attribute__((address_space(1))) unsigned int*)g,
      (__attribute__((address_space(3))) unsigned int*)l, 16, 0, 0);
}

__global__ __launch_bounds__(256) void detect_f32_k(const unsigned short* __restrict__ raw, int n,
                                                    int* __restrict__ flagF){
  int i = blockIdx.x*256 + threadIdx.x;
  if (i < n){
    unsigned e = (raw[i] >> 7) & 0xFFu;
    if (e >= 0xC0u) atomicOr(flagF, 1);
  }
}

// ---- batched conversion with strided-dst support ----
struct CvPack {
  const void* src[11];
  bf16* dst[11];
  int pre[12];
  int rl[11];
  int st[11];
};
__global__ __launch_bounds__(256) void convert_all(CvPack p, const int* __restrict__ flagF){
  int gid = blockIdx.x*256 + threadIdx.x;
  if (gid >= p.pre[11]) return;
  int t = 0;
  while (gid >= p.pre[t+1]) ++t;
  int i = gid - p.pre[t];
  bool f = (*flagF != 0);
  float v = f ? ((const float*)p.src[t])[i] : (float)((const bf16*)p.src[t])[i];
  int row = i / p.rl[t], col = i - row*p.rl[t];
  p.dst[t][(size_t)row*p.st[t] + col] = (bf16)v;
}

__global__ __launch_bounds__(256) void detect_i64(const int* __restrict__ raw, int* __restrict__ flag){
  int i = blockIdx.x*256 + threadIdx.x;
  if (i < 4000 && raw[2*i+1] != 0) atomicOr(flag, 1);   // flag!=0 => int32
}

// conv_idx + degree count fused (cnt pre-zeroed via memset)
__global__ __launch_bounds__(256) void conv_idx(const int* __restrict__ ei_raw,
                                                const int* __restrict__ b_raw,
                                                const int* __restrict__ flag,
                                                int* __restrict__ src, int* __restrict__ dst,
                                                int* __restrict__ bat, int* __restrict__ cnt){
  int i = blockIdx.x*256 + threadIdx.x;
  bool i32 = (*flag != 0);
  if (i < N_EDGES){
    int s = i32 ? ei_raw[i]   : ei_raw[2*i];
    int d = i32 ? ei_raw[N_EDGES + i] : ei_raw[2*(N_EDGES + i)];
    s = min(max(s, 0), N_NODES-1);
    d = min(max(d, 0), N_NODES-1);
    src[i] = s; dst[i] = d;
    atomicAdd(&cnt[d], 1);
  }
  if (i < N_NODES){
    int b = i32 ? b_raw[i] : b_raw[2*i];
    bat[i] = min(max(b, 0), N_GRAPHS-1);
  }
}

// ---------------- parallel scan (3 small dispatches) ----------------
__global__ __launch_bounds__(256) void scanA(const int* __restrict__ cnt, int* __restrict__ fill,
                                             int* __restrict__ bsum, int N){
  __shared__ int s[256];
  int i = blockIdx.x*256 + threadIdx.x;
  int v = (i < N) ? cnt[i] : 0;
  s[threadIdx.x] = v;
  __syncthreads();
  for (int d = 1; d < 256; d <<= 1){
    int t = (threadIdx.x >= d) ? s[threadIdx.x - d] : 0;
    __syncthreads();
    s[threadIdx.x] += t;
    __syncthreads();
  }
  if (i < N) fill[i] = s[threadIdx.x] - v;          // block-exclusive
  if (threadIdx.x == 255) bsum[blockIdx.x] = s[255];
}
__global__ __launch_bounds__(64) void scanB(int* __restrict__ bsum, int nb){
  if (threadIdx.x == 0){
    int a = 0;
    for (int b = 0; b < nb; ++b){ int t = bsum[b]; bsum[b] = a; a += t; }
  }
}
__global__ __launch_bounds__(256) void scanC(const int* __restrict__ bsum, int* __restrict__ fill,
                                             int* __restrict__ row_ptr, int N){
  int i = blockIdx.x*256 + threadIdx.x;
  if (i < N){
    int st = fill[i] + bsum[i >> 8];
    fill[i] = st;
    row_ptr[i] = st;
  }
  if (i == 0) row_ptr[N] = N_EDGES;   // dst clamped -> every edge counted
}

__global__ __launch_bounds__(256) void fill_csr(const int* __restrict__ dst,
                                                int* __restrict__ fill, int* __restrict__ eids){
  int e = blockIdx.x*256 + threadIdx.x;
  if (e < N_EDGES){
    int p = atomicAdd(&fill[dst[e]], 1);
    eids[p] = e;
  }
}

// ---------------- GEMM: C[M][N] = A[M][K](lda) @ Bt[N][K] + bias ----------------
__global__ __launch_bounds__(256)
void gemm_bias(const bf16* __restrict__ A, int lda,
               const bf16* __restrict__ Bt,
               const bf16* __restrict__ bias, bf16* __restrict__ Cout, int ldc,
               int M, int N, int K)
{
  __shared__ bf16 As[128*64];
  __shared__ bf16 Bs[128*64];
  const int tid = threadIdx.x;
  const int lane = tid & 63;
  const int wave = tid >> 6;
  const int m0 = blockIdx.y * 128, n0 = blockIdx.x * 128;
  const int wm = (wave >> 1) * 64, wn = (wave & 1) * 64;
  const int l15 = lane & 15, l4 = lane >> 4;
  const int srow = lane >> 3;
  const int schunk = lane & 7;

  f32x4 acc[4][4] = {};

  for (int k0 = 0; k0 < K; k0 += 64){
    #pragma unroll
    for (int j = 0; j < 4; ++j){
      int r0 = (wave*4 + j)*8;
      int r  = r0 + srow;
      int gc = schunk ^ (r & 7);
      int ga = m0 + r; if (ga >= M) ga = M-1;
      gload_lds16(A  + (size_t)ga*lda      + k0 + gc*8, As + r0*64);
      gload_lds16(Bt + (size_t)(n0 + r)*K  + k0 + gc*8, Bs + r0*64);
    }
    __syncthreads();
    #pragma unroll
    for (int kt = 0; kt < 2; ++kt){
      bf16x8 af[4], bfr[4];
      #pragma unroll
      for (int mt = 0; mt < 4; ++mt){
        int row = wm + mt*16 + l15;
        int p = (kt*4 + l4) ^ (l15 & 7);
        af[mt] = *(const bf16x8*)(As + row*64 + p*8);
      }
      #pragma unroll
      for (int nt = 0; nt < 4; ++nt){
        int row = wn + nt*16 + l15;
        int p = (kt*4 + l4) ^ (l15 & 7);
        bfr[nt] = *(const bf16x8*)(Bs + row*64 + p*8);
      }
      #pragma unroll
      for (int mt = 0; mt < 4; ++mt)
        #pragma unroll
        for (int nt = 0; nt < 4; ++nt)
          acc[mt][nt] = __builtin_amdgcn_mfma_f32_16x16x32_bf16(af[mt], bfr[nt], acc[mt][nt], 0, 0, 0);
    }
    __syncthreads();
  }

  #pragma unroll
  for (int nt = 0; nt < 4; ++nt){
    int col = n0 + wn + nt*16 + l15;
    float bv = (float)bias[col];
    #pragma unroll
    for (int mt = 0; mt < 4; ++mt){
      int rbase = m0 + wm + mt*16 + l4*4;
      #pragma unroll
      for (int r = 0; r < 4; ++r){
        int row = rbase + r;
        if (row < M) Cout[(size_t)row*ldc + col] = (bf16)(acc[mt][nt][r] + bv);
      }
    }
  }
}

// ---------------- occupancy-tuned GEMM for the big z2 GEMM ----------------
// __launch_bounds__(256,4): 128 regs/wave -> 4 waves/SIMD; row-contiguous epilogue.
__global__ __launch_bounds__(256, 4)
void gemm_biasO(const bf16* __restrict__ A, int lda,
                const bf16* __restrict__ Bt,
                const bf16* __restrict__ bias, bf16* __restrict__ Cout, int ldc,
                int M, int N, int K)
{
  __shared__ bf16 As[128*64];
  __shared__ bf16 Bs[128*64];
  const int tid = threadIdx.x;
  const int lane = tid & 63;
  const int wave = tid >> 6;
  const int m0 = blockIdx.y * 128, n0 = blockIdx.x * 128;
  const int wm = (wave >> 1) * 64, wn = (wave & 1) * 64;
  const int l15 = lane & 15, l4 = lane >> 4;
  const int srow = lane >> 3;
  const int schunk = lane & 7;

  f32x4 acc[4][4] = {};

  for (int k0 = 0; k0 < K; k0 += 64){
    #pragma unroll
    for (int j = 0; j < 4; ++j){
      int r0 = (wave*4 + j)*8;
      int r  = r0 + srow;
      int gc = schunk ^ (r & 7);
      int ga = m0 + r; if (ga >= M) ga = M-1;
      gload_lds16(A  + (size_t)ga*lda      + k0 + gc*8, As + r0*64);
      gload_lds16(Bt + (size_t)(n0 + r)*K  + k0 + gc*8, Bs + r0*64);
    }
    __syncthreads();
    #pragma unroll
    for (int kt = 0; kt < 2; ++kt){
      bf16x8 af[4], bfr[4];
      #pragma unroll
      for (int mt = 0; mt < 4; ++mt){
        int row = wm + mt*16 + l15;
        int p = (kt*4 + l4) ^ (l15 & 7);
        af[mt] = *(const bf16x8*)(As + row*64 + p*8);
      }
      #pragma unroll
      for (int nt = 0; nt < 4; ++nt){
        int row = wn + nt*16 + l15;
        int p = (kt*4 + l4) ^ (l15 & 7);
        bfr[nt] = *(const bf16x8*)(Bs + row*64 + p*8);
      }
      #pragma unroll
      for (int mt = 0; mt < 4; ++mt)
        #pragma unroll
        for (int nt = 0; nt < 4; ++nt)
          acc[mt][nt] = __builtin_amdgcn_mfma_f32_16x16x32_bf16(af[mt], bfr[nt], acc[mt][nt], 0, 0, 0);
    }
    __syncthreads();
  }

  float bv[4];
  #pragma unroll
  for (int nt = 0; nt < 4; ++nt) bv[nt] = (float)bias[n0 + wn + nt*16 + l15];
  #pragma unroll
  for (int mt = 0; mt < 4; ++mt){
    int rbase = m0 + wm + mt*16 + l4*4;
    #pragma unroll
    for (int r = 0; r < 4; ++r){
      int row = rbase + r;
      if (row < M){
        #pragma unroll
        for (int nt = 0; nt < 4; ++nt)
          Cout[(size_t)row*ldc + n0 + wn + nt*16 + l15] = (bf16)(acc[mt][nt][r] + bv[nt]);
      }
    }
  }
}

// ---------------- deep-pipelined z-GEMM: BM=256 x BN=128, BK=64, 512 thr, 8 waves ----
// Used for L3 z (K=256).
__global__ __launch_bounds__(512, 1)
void gemm8p_bias(const bf16* __restrict__ A, int lda,
                 const bf16* __restrict__ Bt,
                 const bf16* __restrict__ bias, bf16* __restrict__ Cout, int ldc,
                 int M, int K)
{
  __shared__ bf16 As[3][256*64];
  __shared__ bf16 Bs[3][128*64];
  const int tid = threadIdx.x;
  const int lane = tid & 63;
  const int wave = tid >> 6;                 // 0..7
  const int m0 = blockIdx.y * 256, n0 = blockIdx.x * 128;
  const int wm = (wave >> 1) * 64;           // 4 m-waves x 64 rows
  const int wn = (wave & 1) * 64;            // 2 n-waves x 64 cols
  const int l15 = lane & 15, l4 = lane >> 4;
  const int srow = lane >> 3;                // 0..7
  const int schunk = lane & 7;               // 0..7
  const int NT = K >> 6;

  auto stageA = [&](int t, int j){
    int b = t % 3;
    int r0 = (wave + j*8)*8;
    int r  = r0 + srow;
    int gc = schunk ^ srow;
    int ga = m0 + r; if (ga >= M) ga = M-1;
    gload_lds16(A + (size_t)ga*lda + t*64 + gc*8, &As[b][r0*64]);
  };
  auto stageB = [&](int t, int j){
    int b = t % 3;
    int r0 = (wave + j*8)*8;
    int r  = r0 + srow;
    int gc = schunk ^ srow;
    gload_lds16(Bt + (size_t)(n0 + r)*K + t*64 + gc*8, &Bs[b][r0*64]);
  };

  stageA(0,0); stageA(0,1); stageA(0,2); stageA(0,3); stageB(0,0); stageB(0,1);
  if (NT > 1){ stageA(1,0); stageA(1,1); stageA(1,2); stageA(1,3); stageB(1,0); stageB(1,1); }
  if (NT > 1) asm volatile("s_waitcnt vmcnt(6)" ::: "memory");
  else        asm volatile("s_waitcnt vmcnt(0)" ::: "memory");
  __builtin_amdgcn_s_barrier();

  f32x4 acc[4][4] = {};

  for (int t = 0; t < NT; ++t){
    const bf16* as = &As[t % 3][0];
    const bf16* bs = &Bs[t % 3][0];
    bf16x8 bfr[4][2];
    bf16x8 af[2][2];

    #pragma unroll
    for (int nt2 = 0; nt2 < 4; ++nt2)
      #pragma unroll
      for (int kt = 0; kt < 2; ++kt){
        int row = wn + nt2*16 + l15;
        int p = (kt*4 + l4) ^ (l15 & 7);
        bfr[nt2][kt] = *(const bf16x8*)(bs + row*64 + p*8);
      }
    #pragma unroll
    for (int i = 0; i < 2; ++i)
      #pragma unroll
      for (int kt = 0; kt < 2; ++kt){
        int row = wm + i*16 + l15;
        int p = (kt*4 + l4) ^ (l15 & 7);
        af[i][kt] = *(const bf16x8*)(as + row*64 + p*8);
      }
    if (t + 2 < NT){ stageA(t+2,0); stageA(t+2,1); stageB(t+2,0); }
    __builtin_amdgcn_s_setprio(1);
    #pragma unroll
    for (int i = 0; i < 2; ++i)
      #pragma unroll
      for (int nt2 = 0; nt2 < 4; ++nt2)
        #pragma unroll
        for (int kt = 0; kt < 2; ++kt)
          acc[i][nt2] = __builtin_amdgcn_mfma_f32_16x16x32_bf16(af[i][kt], bfr[nt2][kt], acc[i][nt2], 0, 0, 0);
    __builtin_amdgcn_s_setprio(0);

    #pragma unroll
    for (int i = 0; i < 2; ++i)
      #pragma unroll
      for (int kt = 0; kt < 2; ++kt){
        int row = wm + (2+i)*16 + l15;
        int p = (kt*4 + l4) ^ (l15 & 7);
        af[i][kt] = *(const bf16x8*)(as + row*64 + p*8);
      }
    if (t + 2 < NT){ stageA(t+2,2); stageA(t+2,3); stageB(t+2,1); }
    __builtin_amdgcn_s_setprio(1);
    #pragma unroll
    for (int i = 0; i < 2; ++i)
      #pragma unroll
      for (int nt2 = 0; nt2 < 4; ++nt2)
        #pragma unroll
        for (int kt = 0; kt < 2; ++kt)
          acc[2+i][nt2] = __builtin_amdgcn_mfma_f32_16x16x32_bf16(af[i][kt], bfr[nt2][kt], acc[2+i][nt2], 0, 0, 0);
    __builtin_amdgcn_s_setprio(0);

    if (t < NT - 1){
      if (t + 2 < NT) asm volatile("s_waitcnt vmcnt(6)" ::: "memory");
      else            asm volatile("s_waitcnt vmcnt(0)" ::: "memory");
      __builtin_amdgcn_s_barrier();
    }
  }

  #pragma unroll
  for (int nt2 = 0; nt2 < 4; ++nt2){
    int col = n0 + wn + nt2*16 + l15;
    float bv = (float)bias[col];
    #pragma unroll
    for (int mt = 0; mt < 4; ++mt){
      int rbase = m0 + wm + mt*16 + l4*4;
      #pragma unroll
      for (int r = 0; r < 4; ++r){
        int row = rbase + r;
        if (row < M) Cout[(size_t)row*ldc + col] = (bf16)(acc[mt][nt2][r] + bv);
      }
    }
  }
}

// ---------------- fused PV-projection GEMM (full-K, direct epilogue) ----------------
// OUTMODE 0: out = ELU(acc + bp[col] - deg0*mb[col]) -> bf16 strided
template<int BM, int OUTMODE>
__global__ __launch_bounds__(256)
void gemm_fused(const bf16* __restrict__ A, int lda,
                const bf16* __restrict__ Bt,
                const bf16* __restrict__ bp, const bf16* __restrict__ mb,
                const int* __restrict__ row_ptr,
                bf16* __restrict__ outB, int ldo, float* __restrict__ outF,
                int M, int K)
{
  constexpr int PA    = BM/32;
  constexpr int WCOLS = 128/BM;
  constexpr int WTN   = BM;
  constexpr int NT    = WTN/16;
  __shared__ bf16 As[BM*64];
  __shared__ bf16 Bs[128*64];
  const int tid = threadIdx.x;
  const int lane = tid & 63;
  const int wave = tid >> 6;
  const int m0 = blockIdx.y * BM, n0 = blockIdx.x * 128;
  const int wm = (wave / WCOLS) * 32;
  const int wn = (wave % WCOLS) * WTN;
  const int l15 = lane & 15, l4 = lane >> 4;
  const int srow = lane >> 3;
  const int schunk = lane & 7;

  f32x4 acc[2][NT] = {};

  for (int k0 = 0; k0 < K; k0 += 64){
    #pragma unroll
    for (int j = 0; j < PA; ++j){
      int r0 = (wave*PA + j)*8;
      int r  = r0 + srow;
      int gc = schunk ^ (r & 7);
      int ga = m0 + r; if (ga >= M) ga = M-1;
      gload_lds16(A + (size_t)ga*lda + k0 + gc*8, As + r0*64);
    }
    #pragma unroll
    for (int j = 0; j < 4; ++j){
      int r0 = (wave*4 + j)*8;
      int r  = r0 + srow;
      int gc = schunk ^ (r & 7);
      gload_lds16(Bt + (size_t)(n0 + r)*K + k0 + gc*8, Bs + r0*64);
    }
    __syncthreads();
    #pragma unroll
    for (int kt = 0; kt < 2; ++kt){
      bf16x8 af[2], bfr[NT];
      #pragma unroll
      for (int mt = 0; mt < 2; ++mt){
        int row = wm + mt*16 + l15;
        int p = (kt*4 + l4) ^ (l15 & 7);
        af[mt] = *(const bf16x8*)(As + row*64 + p*8);
      }
      #pragma unroll
      for (int nt = 0; nt < NT; ++nt){
        int row = wn + nt*16 + l15;
        int p = (kt*4 + l4) ^ (l15 & 7);
        bfr[nt] = *(const bf16x8*)(Bs + row*64 + p*8);
      }
      #pragma unroll
      for (int mt = 0; mt < 2; ++mt)
        #pragma unroll
        for (int nt = 0; nt < NT; ++nt)
          acc[mt][nt] = __builtin_amdgcn_mfma_f32_16x16x32_bf16(af[mt], bfr[nt], acc[mt][nt], 0, 0, 0);
    }
    __syncthreads();
  }

  if (OUTMODE == 0){
    float bv[NT], mv[NT];
    #pragma unroll
    for (int nt = 0; nt < NT; ++nt){
      int col = n0 + wn + nt*16 + l15;
      bv[nt] = (float)bp[col];
      mv[nt] = (float)mb[col];
    }
    #pragma unroll
    for (int mt = 0; mt < 2; ++mt){
      int rbase = m0 + wm + mt*16 + l4*4;
      #pragma unroll
      for (int r = 0; r < 4; ++r){
        int row = rbase + r;
        if (row < M){
          bool d0 = (row_ptr[row+1] == row_ptr[row]);
          #pragma unroll
          for (int nt = 0; nt < NT; ++nt){
            int col = n0 + wn + nt*16 + l15;
            float v = acc[mt][nt][r] + bv[nt] - (d0 ? mv[nt] : 0.f);
            v = (v > 0.f) ? v : (__expf(v) - 1.f);
            outB[(size_t)row*ldo + col] = (bf16)v;
          }
        }
      }
    }
  } else {
    #pragma unroll
    for (int mt = 0; mt < 2; ++mt){
      int rbase = m0 + wm + mt*16 + l4*4;
      #pragma unroll
      for (int r = 0; r < 4; ++r){
        int row = rbase + r;
        if (row < M){
          #pragma unroll
          for (int nt = 0; nt < NT; ++nt){
            int col = n0 + wn + nt*16 + l15;
            outF[(size_t)row*128 + col] = acc[mt][nt][r];
          }
        }
      }
    }
  }
}

// ---------------- deterministic split-K PV GEMM (no atomics) ----------------
// z-chunk blockIdx.z computes K range [z*KS, z*KS+KS) and writes its own f32
// partial slice Cacc[z*M*NW + row*NW + col] with plain stores. A reduce pass
// (reduce2_elu / finalize_gate) sums slices + applies bias/deg0/ELU.
template<int BM>
__global__ __launch_bounds__(256)
void gemm_sk(const bf16* __restrict__ A, int lda,
             const bf16* __restrict__ Bt, float* __restrict__ Cacc,
             int M, int K, int KS, int NW)
{
  constexpr int PA    = BM/32;
  constexpr int WCOLS = 128/BM;
  constexpr int WTN   = BM;
  constexpr int NT    = WTN/16;
  __shared__ bf16 As[BM*64];
  __shared__ bf16 Bs[128*64];
  const int tid = threadIdx.x;
  const int lane = tid & 63;
  const int wave = tid >> 6;
  const int m0 = blockIdx.y * BM, n0 = blockIdx.x * 128;
  const int wm = (wave / WCOLS) * 32;
  const int wn = (wave % WCOLS) * WTN;
  const int l15 = lane & 15, l4 = lane >> 4;
  const int srow = lane >> 3;
  const int schunk = lane & 7;
  const int kb = blockIdx.z * KS;
  const int ke = min(K, kb + KS);

  f32x4 acc[2][NT] = {};

  for (int k0 = kb; k0 < ke; k0 += 64){
    #pragma unroll
    for (int j = 0; j < PA; ++j){
      int r0 = (wave*PA + j)*8;
      int r  = r0 + srow;
      int gc = schunk ^ (r & 7);
      int ga = m0 + r; if (ga >= M) ga = M-1;
      gload_lds16(A + (size_t)ga*lda + k0 + gc*8, As + r0*64);
    }
    #pragma unroll
    for (int j = 0; j < 4; ++j){
      int r0 = (wave*4 + j)*8;
      int r  = r0 + srow;
      int gc = schunk ^ (r & 7);
      gload_lds16(Bt + (size_t)(n0 + r)*K + k0 + gc*8, Bs + r0*64);
    }
    __syncthreads();
    #pragma unroll
    for (int kt = 0; kt < 2; ++kt){
      bf16x8 af[2], bfr[NT];
      #pragma unroll
      for (int mt = 0; mt < 2; ++mt){
        int row = wm + mt*16 + l15;
        int p = (kt*4 + l4) ^ (l15 & 7);
        af[mt] = *(const bf16x8*)(As + row*64 + p*8);
      }
      #pragma unroll
      for (int nt = 0; nt < NT; ++nt){
        int row = wn + nt*16 + l15;
        int p = (kt*4 + l4) ^ (l15 & 7);
        bfr[nt] = *(const bf16x8*)(Bs + row*64 + p*8);
      }
      #pragma unroll
      for (int mt = 0; mt < 2; ++mt)
        #pragma unroll
        for (int nt = 0; nt < NT; ++nt)
          acc[mt][nt] = __builtin_amdgcn_mfma_f32_16x16x32_bf16(af[mt], bfr[nt], acc[mt][nt], 0, 0, 0);
    }
    __syncthreads();
  }

  float* Cz = Cacc + (size_t)blockIdx.z * M * NW;
  #pragma unroll
  for (int mt = 0; mt < 2; ++mt){
    int rbase = m0 + wm + mt*16 + l4*4;
    #pragma unroll
    for (int r = 0; r < 4; ++r){
      int row = rbase + r;
      if (row < M){
        #pragma unroll
        for (int nt = 0; nt < NT; ++nt)
          Cz[(size_t)row*NW + n0 + wn + nt*16 + l15] = acc[mt][nt][r];
      }
    }
  }
}

// ---------------- reduce 2 split-K slices + bias + deg0 + ELU -> bf16 strided ----------------
__global__ __launch_bounds__(256)
void reduce2_elu(const float* __restrict__ facc, const bf16* __restrict__ bp,
                 const bf16* __restrict__ mb, const int* __restrict__ row_ptr,
                 int shift, int mask, int total, bf16* __restrict__ out, int ldo)
{
  int idx = blockIdx.x*256 + threadIdx.x;
  if (idx >= total) return;
  int n = idx >> shift, c = idx & mask;
  bool d0 = (row_ptr[n+1] == row_ptr[n]);
  float v = facc[idx] + facc[(size_t)total + idx] + (float)bp[c] - (d0 ? (float)mb[c] : 0.f);
  v = (v > 0.f) ? v : (__expf(v) - 1.f);
  out[(size_t)n*ldo + c] = (bf16)v;
}

// ---------------- L3 finalize fused with gate computation (NO atomics) ----------------
// Sums the 2 split-K slices; writes h3 and gate[n].
__global__ __launch_bounds__(256)
void finalize_gate(const float* __restrict__ facc, const bf16* __restrict__ bp,
                   const bf16* __restrict__ mb, const int* __restrict__ row_ptr,
                   bf16* __restrict__ hout, const bf16* __restrict__ wg,
                   const bf16* __restrict__ bg, float* __restrict__ gate)
{
  __shared__ float wred[4];
  int idx = blockIdx.x*256 + threadIdx.x;     // < N_NODES*128
  int n = idx >> 7, c = idx & 127;
  bool d0 = (row_ptr[n+1] == row_ptr[n]);
  float v = facc[idx] + facc[(size_t)N_NODES*128 + idx]
          + (float)bp[c] - (d0 ? (float)mb[c] : 0.f);
  v = (v > 0.f) ? v : (__expf(v) - 1.f);
  hout[idx] = (bf16)v;
  float gc = v * (float)wg[c];
  #pragma unroll
  for (int o = 32; o; o >>= 1) gc += __shfl_xor(gc, o, 64);
  int wave = threadIdx.x >> 6;
  if ((threadIdx.x & 63) == 0) wred[wave] = gc;
  __syncthreads();
  if ((threadIdx.x & 127) == 0){
    float g = wred[wave] + wred[wave + 1] + (float)bg[0];
    gate[n] = g;
  }
}

// ---------------- atomic-free segmented softmax-pool (batch is sorted) ----------------
__global__ __launch_bounds__(256)
void pool_graphs(const float* __restrict__ gate, const int* __restrict__ bat,
                 const bf16* __restrict__ h, float* __restrict__ gacc)
{
  int b = blockIdx.x;
  int lo = 0, hi = N_NODES;
  while (lo < hi){ int mid = (lo + hi) >> 1; if (bat[mid] < b) lo = mid + 1; else hi = mid; }
  int s = lo;
  lo = s; hi = N_NODES;
  while (lo < hi){ int mid = (lo + hi) >> 1; if (bat[mid] < b + 1) lo = mid + 1; else hi = mid; }
  int e = lo;

  int t = threadIdx.x;
  float m = -3.4e38f;
  for (int n = s + t; n < e; n += 256) m = fmaxf(m, gate[n]);
  #pragma unroll
  for (int o = 32; o; o >>= 1) m = fmaxf(m, __shfl_xor(m, o, 64));
  __shared__ float red[4];
  int wv = t >> 6;
  if ((t & 63) == 0) red[wv] = m;
  __syncthreads();
  m = fmaxf(fmaxf(red[0], red[1]), fmaxf(red[2], red[3]));

  int team = t >> 7, c = t & 127;
  float acc = 0.f, se = 0.f;
  for (int n = s + team; n < e; n += 2){
    float en = __expf(gate[n] - m);
    acc += en * (float)h[(size_t)n*128 + c];
    if (c == 0) se += en;
  }
  __shared__ float accs[256];
  __shared__ float ses[2];
  accs[t] = acc;
  if (c == 0) ses[team] = se;
  __syncthreads();
  if (t < 128){
    float tot = accs[t] + accs[128 + t];
    float S = ses[0] + ses[1];
    gacc[b*128 + t] = tot / (S + 1e-16f);
  }
}

// ---------------- merged M_h precompute (all 3 layers, 1 dispatch) ----------------
struct MhPack { const bf16* wk[3]; const bf16* wq[3]; bf16* wzt[3]; int fin[3]; int c[3]; };
__global__ __launch_bounds__(256)
void gemm_mh_all(MhPack P)
{
  const int L = blockIdx.z >> 3, h = blockIdx.z & 7;
  const int Fin = P.fin[L], C = P.c[L];
  const int nb = Fin >> 7;
  if ((int)blockIdx.x >= nb || (int)blockIdx.y >= nb) return;
  __shared__ bf16 As[128*64];
  __shared__ bf16 Bs[128*64];
  const int ld = 8*C;
  const bf16* Ab = P.wk[L] + h*C;
  const bf16* Bb = P.wq[L] + h*C;
  bf16* Cb = P.wzt[L] + (size_t)h*Fin*Fin;
  const int tid = threadIdx.x;
  const int lane = tid & 63;
  const int wave = tid >> 6;
  const int m0 = blockIdx.y * 128, n0 = blockIdx.x * 128;
  const int wm = (wave >> 1) * 64, wn = (wave & 1) * 64;
  const int l15 = lane & 15, l4 = lane >> 4;
  const int srow = lane >> 3;
  const int schunk = lane & 7;

  f32x4 acc[4][4] = {};

  for (int k0 = 0; k0 < C; k0 += 64){
    #pragma unroll
    for (int j = 0; j < 4; ++j){
      int r0 = (wave*4 + j)*8;
      int r  = r0 + srow;
      int gc = schunk ^ (r & 7);
      gload_lds16(Ab + (size_t)(m0 + r)*ld + k0 + gc*8, As + r0*64);
      gload_lds16(Bb + (size_t)(n0 + r)*ld + k0 + gc*8, Bs + r0*64);
    }
    __syncthreads();
    #pragma unroll
    for (int kt = 0; kt < 2; ++kt){
      bf16x8 af[4], bfr[4];
      #pragma unroll
      for (int mt = 0; mt < 4; ++mt){
        int row = wm + mt*16 + l15;
        int p = (kt*4 + l4) ^ (l15 & 7);
        af[mt] = *(const bf16x8*)(As + row*64 + p*8);
      }
      #pragma unroll
      for (int nt = 0; nt < 4; ++nt){
        int row = wn + nt*16 + l15;
        int p = (kt*4 + l4) ^ (l15 & 7);
        bfr[nt] = *(const bf16x8*)(Bs + row*64 + p*8);
      }
      #pragma unroll
      for (int mt = 0; mt < 4; ++mt)
        #pragma unroll
        for (int nt = 0; nt < 4; ++nt)
          acc[mt][nt] = __builtin_amdgcn_mfma_f32_16x16x32_bf16(af[mt], bfr[nt], acc[mt][nt], 0, 0, 0);
    }
    __syncthreads();
  }

  #pragma unroll
  for (int nt = 0; nt < 4; ++nt){
    int col = n0 + wn + nt*16 + l15;
    #pragma unroll
    for (int mt = 0; mt < 4; ++mt){
      int rbase = m0 + wm + mt*16 + l4*4;
      #pragma unroll
      for (int r = 0; r < 4; ++r)
        Cb[(size_t)(rbase + r)*Fin + col] = (bf16)acc[mt][nt][r];
    }
  }
}

// ---------------- merged Wv/Ws prep (all 3 layers) ----------------
struct WvPack { const void* wv[3]; const void* ws[3]; bf16* bt[3]; int fin[3]; int c[3]; int bx[3]; int by[3]; };
__global__ __launch_bounds__(256)
void prep_wv_all(WvPack P, const int* __restrict__ flagF)
{
  const int L = blockIdx.z;
  if ((int)blockIdx.x >= P.bx[L] || (int)blockIdx.y >= P.by[L]) return;
  __shared__ float t[32][33];
  bool f = (*flagF != 0);
  const int Fin = P.fin[L], C = P.c[L];
  int k0 = blockIdx.x*32, j0 = blockIdx.y*32;
  int x = threadIdx.x & 31, y = threadIdx.x >> 5;
  const void* srcp; int nstride, cb; float sc; int i0;
  if (k0 < 8*Fin){
    int h = k0 / Fin; i0 = k0 - h*Fin;
    srcp = P.wv[L]; nstride = 8*C; cb = h*C + j0; sc = 0.125f;
  } else {
    i0 = k0 - 8*Fin;
    srcp = P.ws[L]; nstride = C; cb = j0; sc = 1.0f;
  }
  #pragma unroll
  for (int ii = 0; ii < 4; ++ii){
    int i = i0 + y + ii*8;
    size_t idx = (size_t)i*nstride + cb + x;
    float v = f ? ((const float*)srcp)[idx] : (float)((const bf16*)srcp)[idx];
    t[y + ii*8][x] = v*sc;
  }
  __syncthreads();
  #pragma unroll
  for (int ii = 0; ii < 4; ++ii){
    int j = j0 + y + ii*8;
    P.bt[L][(size_t)j*(9*Fin) + k0 + x] = (bf16)t[x][y + ii*8];
  }
}

// ---------------- merged small prep (all 3 layers), wave-per-row ----------------
struct SmPack { const bf16* wkc[3]; const void* bq[3]; const void* bv[3]; const void* bs[3];
                int fin[3]; int c[3]; bf16* tz[3]; bf16* bp[3]; bf16* mb[3]; int rb[3]; int bpb[3]; };
__global__ __launch_bounds__(256)
void prep_small_all(SmPack P, const int* __restrict__ flagF)
{
  const int L = blockIdx.z;
  const int Fin = P.fin[L], C = P.c[L];
  const int rb = P.rb[L];
  if ((int)blockIdx.x >= rb + P.bpb[L]) return;
  bool f = (*flagF != 0);
  if ((int)blockIdx.x < rb){
    int wave = threadIdx.x >> 6, lane = threadIdx.x & 63;
    int r = blockIdx.x*4 + wave;            // r < 8*Fin (rb = 8*Fin/4)
    int h = r / Fin, i = r - h*Fin;
    int epc = C >> 6;
    const bf16* wp = P.wkc[L] + (size_t)i*8*C + h*C;
    const void* bqp = P.bq[L];
    float s = 0.f;
    for (int k = 0; k < epc; ++k){
      int c = k*64 + lane;
      float b = f ? ((const float*)bqp)[h*C + c] : (float)((const bf16*)bqp)[h*C + c];
      s += (float)wp[c] * b;
    }
    #pragma unroll
    for (int o = 32; o; o >>= 1) s += __shfl_xor(s, o, 64);
    if (lane == 0) P.tz[L][r] = (bf16)s;
  } else {
    int idx = ((int)blockIdx.x - rb)*256 + threadIdx.x;
    if (idx < C){
      float s = 0.f;
      for (int h = 0; h < 8; ++h)
        s += f ? ((const float*)P.bv[L])[h*C + idx] : (float)((const bf16*)P.bv[L])[h*C + idx];
      s *= 0.125f;
      float bsv = f ? ((const float*)P.bs[L])[idx] : (float)((const bf16*)P.bs[L])[idx];
      P.mb[L][idx] = (bf16)s;
      P.bp[L][idx] = (bf16)(s + bsv);
    }
  }
}

// ---------------- edge phase, wave-per-node rewrite ----------------
// deg capped at 64 (Poisson(8) over 10k nodes: max ~24; P(>64) ~ 1e-40).
template<int Fin, int NHT>
__global__ __launch_bounds__(256)
void node_edge(const bf16* __restrict__ z, int zw, int hbase,
               bf16* __restrict__ AP, int ldP,
               const int* __restrict__ row_ptr, const int* __restrict__ eids,
               const int* __restrict__ srcv, float scale)
{
  constexpr int EPL  = Fin/64;   // elems/lane for full-row ops
  constexpr int EPL2 = EPL/2;    // f32x2 pairs/lane
  constexpr int KC   = Fin/32;   // mfma k-steps
  typedef typename VecT<EPL>::type vecb;
  __shared__ float sw[4][68][12];   // [wave][edge][head] alpha; 12-col pad for 16B-aligned rows

  const int wave = threadIdx.x >> 6;
  const int lane = threadIdx.x & 63;
  const int n = blockIdx.x*4 + wave;            // grid*4 == N_NODES exactly

  const int beg = row_ptr[n];
  int deg = row_ptr[n+1] - beg;
  if (deg > 64) deg = 64;

  bf16* APn = AP + (size_t)n*ldP;

  if (deg == 0){
    vecb zv;
    #pragma unroll
    for (int k = 0; k < EPL; ++k) zv[k] = (bf16)0.f;
    #pragma unroll
    for (int h = 0; h < NHT; ++h)
      *(vecb*)(APn + (size_t)(hbase + h)*Fin + lane*EPL) = zv;
    return;
  }

  // per-lane src node index (clamped so every lane holds a valid index)
  int e_ld = (lane < deg) ? lane : 0;
  int srcReg = srcv[eids[beg + e_ld]];

  const int nc = (deg + 15) >> 4;               // 16-edge chunks, <=4
  const int l15 = lane & 15, l4 = lane >> 4;
  const int h   = l15 & (NHT-1);
  const bf16* zp = z + (size_t)n*zw + (size_t)h*Fin + l4*8;

  // ---- scores via MFMA ----
  f32x4 sacc[4];
  #pragma unroll
  for (int c = 0; c < 4; ++c) sacc[c] = (f32x4){0.f,0.f,0.f,0.f};

  #pragma unroll
  for (int c = 0; c < 4; ++c){
    if (c < nc){
      int sn = __shfl(srcReg, c*16 + l15, 64);  // edge for this lane's A-row
      const bf16* ap = AP + (size_t)sn*ldP + 8*Fin + l4*8;
      f32x4 s = (f32x4){0.f,0.f,0.f,0.f};
      #pragma unroll
      for (int k = 0; k < KC; ++k){
        bf16x8 af = *(const bf16x8*)(ap + k*32);
        bf16x8 bv = *(const bf16x8*)(zp + k*32);
        s = __builtin_amdgcn_mfma_f32_16x16x32_bf16(af, bv, s, 0, 0, 0);
      }
      sacc[c] = s;
    }
  }

  // ---- softmax over edges, all heads at once (col = l15 = head) ----
  float m = -3.4e38f;
  #pragma unroll
  for (int c = 0; c < 4; ++c){
    if (c < nc){
      #pragma unroll
      for (int r = 0; r < 4; ++r){
        int row = c*16 + l4*4 + r;
        float v = sacc[c][r]*scale;
        sacc[c][r] = v;
        if (row < deg) m = fmaxf(m, v);
      }
    }
  }
  m = fmaxf(m, __shfl_xor(m, 16, 64));
  m = fmaxf(m, __shfl_xor(m, 32, 64));
  float ssum = 0.f;
  #pragma unroll
  for (int c = 0; c < 4; ++c){
    if (c < nc){
      #pragma unroll
      for (int r = 0; r < 4; ++r){
        int row = c*16 + l4*4 + r;
        float e = (row < deg) ? __expf(sacc[c][r] - m) : 0.f;
        sacc[c][r] = e;
        ssum += e;
      }
    }
  }
  ssum += __shfl_xor(ssum, 16, 64);
  ssum += __shfl_xor(ssum, 32, 64);
  float inv = 1.f/(ssum + 1e-16f);

  if (l15 < NHT){
    #pragma unroll
    for (int c = 0; c < 4; ++c){
      if (c < nc){
        #pragma unroll
        for (int r = 0; r < 4; ++r)
          sw[wave][c*16 + l4*4 + r][l15] = sacc[c][r]*inv;
      }
    }
  }
  // zero the 4 pad rows past the last chunk (PV batches may overrun by <=3)
  if (lane < 4*NHT)
    sw[wave][nc*16 + (lane >> 3)][lane & 7] = 0.f;
  // same-wave LDS write->read: compiler inserts lgkmcnt; no barrier needed

  // ---- PV: P[h] = sum_e alpha[e][h] * x_src[e], x read once, 4-edge batches ----
  f32x2 acc[NHT][EPL2];
  #pragma unroll
  for (int hh = 0; hh < NHT; ++hh)
    #pragma unroll
    for (int p = 0; p < EPL2; ++p) acc[hh][p] = (f32x2){0.f,0.f};

  for (int i0 = 0; i0 < deg; i0 += 4){
    int sn0 = __shfl(srcReg, i0,   64);
    int sn1 = __shfl(srcReg, i0+1, 64);   // >=deg -> alpha 0; wraps >=64 -> valid idx
    int sn2 = __shfl(srcReg, i0+2, 64);
    int sn3 = __shfl(srcReg, i0+3, 64);
    vecb hv0 = *(const vecb*)(AP + (size_t)sn0*ldP + 8*Fin + lane*EPL);
    vecb hv1 = *(const vecb*)(AP + (size_t)sn1*ldP + 8*Fin + lane*EPL);
    vecb hv2 = *(const vecb*)(AP + (size_t)sn2*ldP + 8*Fin + lane*EPL);
    vecb hv3 = *(const vecb*)(AP + (size_t)sn3*ldP + 8*Fin + lane*EPL);
    #pragma unroll
    for (int j = 0; j < 4; ++j){
      int e = i0 + j;
      vecb hv = (j == 0) ? hv0 : (j == 1) ? hv1 : (j == 2) ? hv2 : hv3;
      f32x4 w0 = *(const f32x4*)&sw[wave][e][0];
      f32x4 w1 = (NHT == 8) ? *(const f32x4*)&sw[wave][e][4] : w0;
      f32x2 xf[EPL2];
      const u32* up = (const u32*)&hv;
      #pragma unroll
      for (int p = 0; p < EPL2; ++p){
        u32 u = up[p];
        xf[p] = (f32x2){ __uint_as_float(u << 16), __uint_as_float(u & 0xffff0000u) };
      }
      #pragma unroll
      for (int hh = 0; hh < NHT; ++hh){
        float w = (hh < 4) ? w0[hh] : w1[hh-4];
        f32x2 wv = (f32x2){w, w};
        #pragma unroll
        for (int p = 0; p < EPL2; ++p)
          acc[hh][p] += wv * xf[p];
      }
    }
  }

  #pragma unroll
  for (int hh = 0; hh < NHT; ++hh){
    vecb o;
    #pragma unroll
    for (int p = 0; p < EPL2; ++p){
      o[2*p]   = (bf16)acc[hh][p][0];
      o[2*p+1] = (bf16)acc[hh][p][1];
    }
    *(vecb*)(APn + (size_t)(hbase + hh)*Fin + lane*EPL) = o;
  }
}

__global__ __launch_bounds__(64) void final_fc(const float* __restrict__ gacc, const bf16* __restrict__ wfc,
                                               const bf16* __restrict__ bfc, void* __restrict__ out,
                                               const int* __restrict__ flagF){
  int g = blockIdx.x;
  int o = threadIdx.x;
  if (o < 10){
    float s = (float)bfc[o];
    for (int c = 0; c < 128; ++c) s += gacc[g*128 + c]*(float)wfc[c*10 + o];
    if (*flagF) ((float*)out)[(size_t)g*10 + o] = s;
    else        ((bf16*)out)[(size_t)g*10 + o]  = (bf16)s;
  }
}

extern "C" void kernel_launch(void* const* d_in, const int* in_sizes, int n_in,
                              void* d_out, int out_size, void* d_ws, size_t ws_size,
                              hipStream_t stream)
{
  const int* ei   = (const int*)d_in[1];
  const int* braw = (const int*)d_in[2];

  // ---- workspace plan (arena-aliased); adaptive A2 size for one-shot layer-2 ----
  bf16 *Wzt1=0,*Wzt2=0,*Wzt3=0,*Wvt1=0,*Wvt2=0,*Wvt3=0;
  float *facc=0,*gate=0;
  bf16 *tz1=0,*tz2=0,*tz3=0,*bp1=0,*mb1=0,*bp2=0,*mb2=0,*bp3=0,*mb3=0,*h3=0;
  bf16 *cwg=0,*cbg=0,*cwfc=0,*cbfc=0;
  int *src=0,*dst=0,*bat=0,*cnt=0,*row_ptr=0,*fillp=0,*eids=0,*flagbuf=0;
  char *A1=0, *A2=0;

  auto plan = [&](bool big)->size_t{
    size_t off = 0;
    auto A = [&](size_t bytes)->char*{
      char* p = (char*)d_ws + off;
      off += (bytes + 255) & ~(size_t)255;
      return p;
    };
    A1 = A(92160000);
    A2 = A(big ? 81920000 : 46080000);
    Wzt1 = (bf16*)A((size_t)8*128*128*2);
    Wzt2 = (bf16*)A((size_t)8*512*512*2);
    Wzt3 = (bf16*)A((size_t)8*256*256*2);
    Wvt1 = (bf16*)A((size_t)512*9*128*2);
    Wvt2 = (bf16*)A((size_t)256*9*512*2);
    Wvt3 = (bf16*)A((size_t)128*9*256*2);
    facc = (float*)A((size_t)N_NODES*512*4);
    tz1  = (bf16*)A(8*128*2);
    tz2  = (bf16*)A(8*512*2);
    tz3  = (bf16*)A(8*256*2);
    bp1  = (bf16*)A(512*2);  mb1 = (bf16*)A(512*2);
    bp2  = (bf16*)A(256*2);  mb2 = (bf16*)A(256*2);
    bp3  = (bf16*)A(128*2);  mb3 = (bf16*)A(128*2);
    h3   = (bf16*)A((size_t)N_NODES*128*2);
    src  = (int*)A((size_t)N_EDGES*4);
    dst  = (int*)A((size_t)N_EDGES*4);
    bat  = (int*)A((size_t)N_NODES*4);
    cnt  = (int*)A((size_t)N_NODES*4);
    row_ptr = (int*)A((size_t)(N_NODES+1)*4);
    fillp= (int*)A((size_t)N_NODES*4);
    eids = (int*)A((size_t)N_EDGES*4);
    flagbuf = (int*)A(16384);
    gate = (float*)A((size_t)N_NODES*4);
    unsigned* poolz = (unsigned*)A((size_t)(64 + 64 + 64*128)*4);
    (void)poolz;
    cwg  = (bf16*)A(128*2);
    cbg  = (bf16*)A(2*2);
    cwfc = (bf16*)A(1280*2);
    cbfc = (bf16*)A(10*2);
    return off;
  };

  bool big = (plan(true) <= ws_size);
  if (!big && plan(false) > ws_size) return;   // floor plan doesn't fit; visible failure
  plan(big);
  unsigned* poolz = (unsigned*)((char*)gate + (((size_t)N_NODES*4 + 255) & ~(size_t)255));

  int* flagI = flagbuf;
  int* flagF = flagbuf + 1;
  int* bsum  = (int*)((char*)flagbuf + 8192);
  float*    gacc = (float*)(poolz + 128);

  bf16* AP1 = (bf16*)A2;   const int ldP1 = 1152;   // [P(1024)|x(128)]
  bf16* z1  = (bf16*)A1;
  bf16* AP2 = (bf16*)A1;   const int ldP2 = 4608;   // [P(4096)|h1(512)]
  bf16* z2  = (bf16*)A2;                            // group (2048w) or big (4096w)
  bf16* AP3 = (bf16*)A2;   const int ldP3 = 2304;   // [P(2048)|h2(256)]
  bf16* z3  = (bf16*)A1;
  bf16* wq1c = (bf16*)(A1 + 48000000);  bf16* wk1c = wq1c + 128*4096;
  bf16* wq2c = wk1c + 128*4096;         bf16* wk2c = wq2c + 512*2048;
  bf16* wq3c = wk2c + 512*2048;         bf16* wk3c = wq3c + 256*1024;

  // ---- detection ----
  hipMemsetAsync(flagbuf, 0, 16384, stream);
  {
    int nprobe = in_sizes[0] < 32768 ? in_sizes[0] : 32768;
    detect_f32_k<<<(nprobe + 255)/256, 256, 0, stream>>>((const unsigned short*)d_in[0], nprobe, flagF);
    detect_i64<<<16, 256, 0, stream>>>(ei, flagI);
  }

  // ---- batched conversion ----
  {
    CvPack p;
    const int CIDX[11] = {0, 3, 5, 11, 13, 19, 21, 27, 28, 29, 30};
    bf16* CDST[11] = {AP1 + 1024, wq1c, wk1c, wq2c, wk2c, wq3c, wk3c, cwg, cbg, cwfc, cbfc};
    int tot = 0;
    for (int t = 0; t < 11; ++t){
      p.src[t] = d_in[CIDX[t]];
      p.dst[t] = CDST[t];
      p.pre[t] = tot;
      int n = in_sizes[CIDX[t]];
      tot += n;
      if (t == 0){ p.rl[t] = 128; p.st[t] = 1152; }
      else       { p.rl[t] = n;   p.st[t] = n;    }
    }
    p.pre[11] = tot;
    convert_all<<<(tot + 255)/256, 256, 0, stream>>>(p, flagF);
  }

  // ---- indices + CSR (parallel scan) ----
  hipMemsetAsync(cnt, 0, (size_t)N_NODES*4, stream);
  conv_idx<<<(N_EDGES + 255)/256, 256, 0, stream>>>(ei, braw, flagI, src, dst, bat, cnt);
  scanA<<<40, 256, 0, stream>>>(cnt, fillp, bsum, N_NODES);
  scanB<<<1, 64, 0, stream>>>(bsum, 40);
  scanC<<<40, 256, 0, stream>>>(bsum, fillp, row_ptr, N_NODES);
  fill_csr<<<(N_EDGES + 255)/256, 256, 0, stream>>>(dst, fillp, eids);

  // ---- merged setup ----
  {
    MhPack mp;
    mp.wk[0]=wk1c; mp.wk[1]=wk2c; mp.wk[2]=wk3c;
    mp.wq[0]=wq1c; mp.wq[1]=wq2c; mp.wq[2]=wq3c;
    mp.wzt[0]=Wzt1; mp.wzt[1]=Wzt2; mp.wzt[2]=Wzt3;
    mp.fin[0]=128; mp.fin[1]=512; mp.fin[2]=256;
    mp.c[0]=512; mp.c[1]=256; mp.c[2]=128;
    gemm_mh_all<<<dim3(4,4,24), 256, 0, stream>>>(mp);

    WvPack wp;
    wp.wv[0]=d_in[7];  wp.wv[1]=d_in[15]; wp.wv[2]=d_in[23];
    wp.ws[0]=d_in[9];  wp.ws[1]=d_in[17]; wp.ws[2]=d_in[25];
    wp.bt[0]=Wvt1; wp.bt[1]=Wvt2; wp.bt[2]=Wvt3;
    wp.fin[0]=128; wp.fin[1]=512; wp.fin[2]=256;
    wp.c[0]=512; wp.c[1]=256; wp.c[2]=128;
    wp.bx[0]=36; wp.bx[1]=144; wp.bx[2]=72;
    wp.by[0]=16; wp.by[1]=8;   wp.by[2]=4;
    prep_wv_all<<<dim3(144,16,3), 256, 0, stream>>>(wp, flagF);

    SmPack sp;
    sp.wkc[0]=wk1c; sp.wkc[1]=wk2c; sp.wkc[2]=wk3c;
    sp.bq[0]=d_in[4];  sp.bq[1]=d_in[12]; sp.bq[2]=d_in[20];
    sp.bv[0]=d_in[8];  sp.bv[1]=d_in[16]; sp.bv[2]=d_in[24];
    sp.bs[0]=d_in[10]; sp.bs[1]=d_in[18]; sp.bs[2]=d_in[26];
    sp.fin[0]=128; sp.fin[1]=512; sp.fin[2]=256;
    sp.c[0]=512; sp.c[1]=256; sp.c[2]=128;
    sp.tz[0]=tz1; sp.tz[1]=tz2; sp.tz[2]=tz3;
    sp.bp[0]=bp1; sp.bp[1]=bp2; sp.bp[2]=bp3;
    sp.mb[0]=mb1; sp.mb[1]=mb2; sp.mb[2]=mb3;
    sp.rb[0]=256;  sp.rb[1]=1024; sp.rb[2]=512;   // 8*Fin/4
    sp.bpb[0]=2;   sp.bpb[1]=1;   sp.bpb[2]=1;    // ceil(C/256)
    prep_small_all<<<dim3(1025,1,3), 256, 0, stream>>>(sp, flagF);
  }

  const int MT = (N_NODES + 127)/128;   // 79
  const int NB = N_NODES/4;             // node_edge: 4 nodes per block (wave-per-node)
  const int MT32 = (N_NODES + 31)/32;   // 313
  const int MT256 = (N_NODES + 255)/256; // 40
  const float sc1 = 1.0f/sqrtf(512.f), sc2 = 1.0f/sqrtf(256.f), sc3 = 1.0f/sqrtf(128.f);

  // ================= layer 1 (Fin=128, C=512) =================
  gemm_bias<<<dim3(8, MT), 256, 0, stream>>>(AP1 + 1024, ldP1, Wzt1, tz1, z1, 1024, N_NODES, 1024, 128);
  node_edge<128,8><<<NB, 256, 0, stream>>>(z1, 1024, 0, AP1, ldP1, row_ptr, eids, src, sc1);
  gemm_fused<32,0><<<dim3(4, MT32), 256, 0, stream>>>(AP1, ldP1, Wvt1, bp1, mb1, row_ptr,
                                                      AP2 + 4096, ldP2, (float*)0, N_NODES, 1152);

  // ================= layer 2 (Fin=512, C=256) =================
  if (big){
    gemm_biasO<<<dim3(32, MT), 256, 0, stream>>>(AP2 + 4096, ldP2, Wzt2, tz2, z2, 4096, N_NODES, 4096, 512);
    node_edge<512,8><<<NB, 256, 0, stream>>>(z2, 4096, 0, AP2, ldP2, row_ptr, eids, src, sc2);
  } else {
    for (int g = 0; g < 2; ++g){
      gemm_bias<<<dim3(16, MT), 256, 0, stream>>>(AP2 + 4096, ldP2, Wzt2 + (size_t)g*4*512*512, tz2 + g*4*512, z2, 2048, N_NODES, 2048, 512);
      node_edge<512,4><<<NB, 256, 0, stream>>>(z2, 2048, g*4, AP2, ldP2, row_ptr, eids, src, sc2);
    }
  }
  // deterministic split-K PV: 2 z-chunks -> f32 partials in facc, then fused reduce
  gemm_sk<32><<<dim3(2, MT32, 2), 256, 0, stream>>>(AP2, ldP2, Wvt2, facc, N_NODES, 4608, 2304, 256);
  reduce2_elu<<<(N_NODES*256)/256, 256, 0, stream>>>(facc, bp2, mb2, row_ptr, 8, 255, N_NODES*256,
                                                     AP3 + 2048, ldP3);

  // ================= layer 3 (Fin=256, C=128) =================
  gemm8p_bias<<<dim3(16, MT256), 512, 0, stream>>>(AP3 + 2048, ldP3, Wzt3, tz3, z3, 2048, N_NODES, 256);
  node_edge<256,8><<<NB, 256, 0, stream>>>(z3, 2048, 0, AP3, ldP3, row_ptr, eids, src, sc3);
  gemm_sk<32><<<dim3(1, MT32, 2), 256, 0, stream>>>(AP3, ldP3, Wvt3, facc, N_NODES, 2304, 1152, 128);
  finalize_gate<<<(N_NODES*128)/256, 256, 0, stream>>>(facc, bp3, mb3, row_ptr, h3, cwg, cbg, gate);

  // ---- atomic-free global attention pooling + fc ----
  pool_graphs<<<N_GRAPHS, 256, 0, stream>>>(gate, bat, h3, gacc);
  final_fc<<<N_GRAPHS, 64, 0, stream>>>(gacc, cwfc, cbfc, d_out, flagF);
}